// Round 10
// baseline (449.716 us; speedup 1.0000x reference)
//
#include <hip/hip_runtime.h>
#include <hip/hip_fp16.h>

#define S_LEN 2048
#define DKV 64
#define NBH 32
#define CTX_ELEMS ((size_t)NBH * S_LEN * DKV)

using half8 = __attribute__((ext_vector_type(8))) _Float16;
using half4 = __attribute__((ext_vector_type(4))) _Float16;
using f32x4 = __attribute__((ext_vector_type(4))) float;
using u32x4 = __attribute__((ext_vector_type(4))) unsigned int;

#define MFMA16x32(a, b, c) __builtin_amdgcn_mfma_f32_16x16x32_f16((a), (b), (c), 0, 0, 0)

// ---------------------------------------------------------------------------
// Runtime mask-dtype detection (1-byte bool vs 4-byte int/float 0/1).
// ---------------------------------------------------------------------------
__global__ void detect_mask_kernel(const unsigned char* __restrict__ mask,
                                   int* __restrict__ flag) {
  __shared__ int nz0s, nzos;
  if (threadIdx.x == 0) { nz0s = 0; nzos = 0; }
  __syncthreads();
  int nz0 = 0, nzo = 0;
  for (int i = threadIdx.x; i < 65536; i += 256) {
    unsigned char b = mask[i];
    if (b) { if ((i & 3) == 0) nz0++; else nzo++; }
  }
  atomicAdd(&nz0s, nz0);
  atomicAdd(&nzos, nzo);
  __syncthreads();
  if (threadIdx.x == 0) *flag = (nz0s > 0 && nzos > 0) ? 0 : 1;
}

// ---------------------------------------------------------------------------
// Pack mask -> 1 bit per element. Bit f of dword bits[f>>5] = (mask[f] != 0).
// int32 path: ballot-based, no LDS, no barriers (lane l <-> element base+l).
// byte path: legacy LDS nibble path (block-uniform branch).
// ---------------------------------------------------------------------------
__global__ void pack_mask_kernel(const void* __restrict__ maskv,
                                 const int* __restrict__ flag,
                                 unsigned int* __restrict__ bits) {
  __shared__ unsigned char nib[256];
  const bool w4 = (*flag) != 0;
  const int tid = threadIdx.x;
  if (w4) {
    const unsigned int* m32 = (const unsigned int*)maskv;
    const int w = tid >> 6;
    const int lane = tid & 63;
    size_t base = ((size_t)blockIdx.x * 4 + w) * (256 * 64);
    for (int i = 0; i < 256; ++i) {
      unsigned int v = __builtin_nontemporal_load(m32 + base + lane);
      unsigned long long b = __ballot(v != 0u);
      if (lane < 2) bits[(base >> 5) + lane] = (unsigned int)(b >> (lane * 32));
      base += 64;
    }
  } else {
    const unsigned int* m32 = (const unsigned int*)maskv;
    for (int it = 0; it < 64; ++it) {
      const size_t e0 = ((size_t)blockIdx.x * 64 + it) * 1024;
      const size_t ei = e0 + (size_t)tid * 4;
      unsigned int b = __builtin_nontemporal_load(m32 + (ei >> 2));
      unsigned int nv = ((b & 0xffu) ? 1u : 0u) | ((b & 0xff00u) ? 2u : 0u) |
                        ((b & 0xff0000u) ? 4u : 0u) | ((b & 0xff000000u) ? 8u : 0u);
      __syncthreads();
      nib[tid] = (unsigned char)nv;
      __syncthreads();
      if (tid < 32) {
        unsigned int dw = 0;
#pragma unroll
        for (int t = 0; t < 8; ++t)
          dw |= ((unsigned int)nib[tid * 8 + t]) << (t * 4);
        bits[(e0 >> 5) + tid] = dw;
      }
    }
  }
}

// ---------------------------------------------------------------------------
// fp32 -> fp16 elementwise with scale (Q gets 0.125 folded in, K gets 1.0).
// ---------------------------------------------------------------------------
__global__ void convert_f32_f16_kernel(const float* __restrict__ src,
                                       _Float16* __restrict__ dst, float scale) {
  size_t i = (size_t)blockIdx.x * blockDim.x + threadIdx.x;
  f32x4 v = *(const f32x4*)(src + i * 4);
  half4 h;
#pragma unroll
  for (int j = 0; j < 4; j++) h[j] = (_Float16)(v[j] * scale);
  *(half4*)(dst + i * 4) = h;
}

// ---------------------------------------------------------------------------
// V [bh][k][d] fp32 -> VT [bh][d][k] fp16.
// ---------------------------------------------------------------------------
__global__ void transpose_v_kernel(const float* __restrict__ V,
                                   _Float16* __restrict__ VT) {
  __shared__ _Float16 t[64][68];
  const int bh = blockIdx.y;
  const int k0 = blockIdx.x * 64;
  const float* Vb = V + ((size_t)bh * S_LEN + k0) * DKV;
#pragma unroll
  for (int it = 0; it < 4; it++) {
    int idx = threadIdx.x + it * 256;
    int kl = idx >> 4;
    int dq = (idx & 15) * 4;
    f32x4 v = *(const f32x4*)(Vb + (size_t)kl * DKV + dq);
#pragma unroll
    for (int j = 0; j < 4; j++) t[kl][dq + j] = (_Float16)v[j];
  }
  __syncthreads();
  _Float16* VTb = VT + (size_t)bh * DKV * S_LEN;
#pragma unroll
  for (int it = 0; it < 4; it++) {
    int idx = threadIdx.x + it * 256;
    int d = idx >> 4;
    int kq = (idx & 15) * 4;
    half4 h;
#pragma unroll
    for (int j = 0; j < 4; j++) h[j] = t[kq + j][d];
    *(half4*)(VTb + (size_t)d * S_LEN + k0 + kq) = h;
  }
}

// ---------------------------------------------------------------------------
// Main attention v8 (= v7 + register-direct attn stores + prescaled Q +
// cbuf/pbuf LDS aliasing). Each wave owns a 32-row q-tile; 8 waves =
// 4 q32-tiles x 2 k-halves; no-max softmax; grid 512.
// ---------------------------------------------------------------------------
__global__ __launch_bounds__(512, 2)
void attn_v8_kernel(const _Float16* __restrict__ QH, const _Float16* __restrict__ KH,
                    const _Float16* __restrict__ VT, const unsigned int* __restrict__ bits,
                    float* __restrict__ out) {
  // pbuf [8][32][40] fp16 (20480 B) aliased with cbuf [4][32][64] f32
  // (32768 B); lifetimes separated by the post-pass-2 barrier.
  __shared__ __align__(16) unsigned char smem[32768];
  __shared__ float zbuf[4][2][32];
  _Float16 (*pbuf)[32][40] = (_Float16 (*)[32][40])smem;
  float (*cbuf)[32][64] = (float (*)[32][64])smem;

  const int tid = threadIdx.x;
  const int w = tid >> 6;
  const int lane = tid & 63;
  const int g = lane >> 4;
  const int c = lane & 15;
  const int tb = w >> 1;         // q32-tile within block (0..3)
  const int half = w & 1;        // k-half: kt4 in [half*8, half*8+8)

  // XCD-chunked swizzle (512 % 8 == 0 -> bijective).
  const int phys = blockIdx.x;
  const int orig = (phys & 7) * 64 + (phys >> 3);
  const int tile = orig * 4 + tb;          // 0..2047 (q32 tiles)
  const int bh = tile >> 6;
  const int q0 = (tile & 63) << 5;

  // Q fragments for row-tiles A (q0..q0+15) and B (q0+16..q0+31); Q prescaled.
  const _Float16* qpA = QH + ((size_t)(bh * S_LEN + q0 + c)) * DKV + g * 8;
  const half8 aA0 = *(const half8*)qpA;
  const half8 aA1 = *(const half8*)(qpA + 32);
  const _Float16* qpB = qpA + 16 * DKV;
  const half8 aB0 = *(const half8*)qpB;
  const half8 aB1 = *(const half8*)(qpB + 32);

  const _Float16* Kb = KH + (size_t)bh * S_LEN * DKV;
  const unsigned int* bq = bits + ((size_t)(bh * S_LEN + q0)) * (S_LEN / 32);

  float ZsA[4] = {0.0f, 0.0f, 0.0f, 0.0f};
  float ZsB[4] = {0.0f, 0.0f, 0.0f, 0.0f};

  // ---------------- pass 1: Z = sum over unmasked exp(s) -------------------
  for (int kt4 = half * 8; kt4 < half * 8 + 8; ++kt4) {
#pragma unroll
    for (int sub = 0; sub < 4; ++sub) {
      const int kt = kt4 * 4 + sub;
      unsigned int mwA[4], mwB[4];
#pragma unroll
      for (int e = 0; e < 4; e++) {
        mwA[e] = bq[(size_t)(g * 4 + e) * (S_LEN / 32) + kt];
        mwB[e] = bq[(size_t)(16 + g * 4 + e) * (S_LEN / 32) + kt];
      }
      const _Float16* kp = Kb + ((size_t)(kt * 32 + c)) * DKV + g * 8;
      half8 k00 = *(const half8*)kp;
      half8 k01 = *(const half8*)(kp + 32);
      half8 k10 = *(const half8*)(kp + 16 * DKV);
      half8 k11 = *(const half8*)(kp + 16 * DKV + 32);
      f32x4 acA0 = (f32x4)0.0f, acA1 = (f32x4)0.0f;
      f32x4 acB0 = (f32x4)0.0f, acB1 = (f32x4)0.0f;
      acA0 = MFMA16x32(aA0, k00, acA0);
      acA0 = MFMA16x32(aA1, k01, acA0);
      acB0 = MFMA16x32(aB0, k00, acB0);
      acB0 = MFMA16x32(aB1, k01, acB0);
      acA1 = MFMA16x32(aA0, k10, acA1);
      acA1 = MFMA16x32(aA1, k11, acA1);
      acB1 = MFMA16x32(aB0, k10, acB1);
      acB1 = MFMA16x32(aB1, k11, acB1);
#pragma unroll
      for (int e = 0; e < 4; e++) {
        float pA0 = ((mwA[e] >> c) & 1u) ? 0.0f : __expf(acA0[e]);
        float pA1 = ((mwA[e] >> (16 + c)) & 1u) ? 0.0f : __expf(acA1[e]);
        float pB0 = ((mwB[e] >> c) & 1u) ? 0.0f : __expf(acB0[e]);
        float pB1 = ((mwB[e] >> (16 + c)) & 1u) ? 0.0f : __expf(acB1[e]);
        ZsA[e] += pA0 + pA1;
        ZsB[e] += pB0 + pB1;
      }
    }
  }
  // merge the 16 c-lanes sharing each row
#pragma unroll
  for (int off = 1; off < 16; off <<= 1) {
#pragma unroll
    for (int e = 0; e < 4; e++) {
      ZsA[e] += __shfl_xor(ZsA[e], off, 64);
      ZsB[e] += __shfl_xor(ZsB[e], off, 64);
    }
  }
  if (c == 0) {
#pragma unroll
    for (int e = 0; e < 4; e++) {
      zbuf[tb][half][g * 4 + e] = ZsA[e];
      zbuf[tb][half][16 + g * 4 + e] = ZsB[e];
    }
  }
  __syncthreads();
  float lZA[4], lZB[4];
#pragma unroll
  for (int e = 0; e < 4; e++) {
    lZA[e] = __logf(zbuf[tb][0][g * 4 + e] + zbuf[tb][1][g * 4 + e]);
    lZB[e] = __logf(zbuf[tb][0][16 + g * 4 + e] + zbuf[tb][1][16 + g * 4 + e]);
  }

  // ---------------- pass 2: attn = exp(s - lnZ), PV ------------------------
  f32x4 ctxA[4], ctxB[4];
#pragma unroll
  for (int nn = 0; nn < 4; nn++) { ctxA[nn] = (f32x4)0.0f; ctxB[nn] = (f32x4)0.0f; }

  const _Float16* Vb = VT + (size_t)bh * DKV * S_LEN;
  float* attn_base = out + CTX_ELEMS + ((size_t)(bh * S_LEN + q0)) * S_LEN;

  for (int kt4 = half * 8; kt4 < half * 8 + 8; ++kt4) {
#pragma unroll
    for (int sub = 0; sub < 4; ++sub) {
      const int kt = kt4 * 4 + sub;
      unsigned int mwA[4], mwB[4];
#pragma unroll
      for (int e = 0; e < 4; e++) {
        mwA[e] = bq[(size_t)(g * 4 + e) * (S_LEN / 32) + kt];
        mwB[e] = bq[(size_t)(16 + g * 4 + e) * (S_LEN / 32) + kt];
      }
      const _Float16* kp = Kb + ((size_t)(kt * 32 + c)) * DKV + g * 8;
      half8 k00 = *(const half8*)kp;
      half8 k01 = *(const half8*)(kp + 32);
      half8 k10 = *(const half8*)(kp + 16 * DKV);
      half8 k11 = *(const half8*)(kp + 16 * DKV + 32);
      f32x4 acA0 = (f32x4)0.0f, acA1 = (f32x4)0.0f;
      f32x4 acB0 = (f32x4)0.0f, acB1 = (f32x4)0.0f;
      acA0 = MFMA16x32(aA0, k00, acA0);
      acA0 = MFMA16x32(aA1, k01, acA0);
      acB0 = MFMA16x32(aB0, k00, acB0);
      acB0 = MFMA16x32(aB1, k01, acB0);
      acA1 = MFMA16x32(aA0, k10, acA1);
      acA1 = MFMA16x32(aA1, k11, acA1);
      acB1 = MFMA16x32(aB0, k10, acB1);
      acB1 = MFMA16x32(aB1, k11, acB1);

      float* ab = attn_base + kt * 32 + c;
#pragma unroll
      for (int e = 0; e < 4; e++) {
        float pA0 = ((mwA[e] >> c) & 1u) ? 0.0f : __expf(acA0[e] - lZA[e]);
        float pA1 = ((mwA[e] >> (16 + c)) & 1u) ? 0.0f : __expf(acA1[e] - lZA[e]);
        float pB0 = ((mwB[e] >> c) & 1u) ? 0.0f : __expf(acB0[e] - lZB[e]);
        float pB1 = ((mwB[e] >> (16 + c)) & 1u) ? 0.0f : __expf(acB1[e] - lZB[e]);
        // fp16 copies into LDS feed the PV A-fragment transpose
        pbuf[w][g * 4 + e][c] = (_Float16)pA0;
        pbuf[w][g * 4 + e][16 + c] = (_Float16)pA1;
        pbuf[w][16 + g * 4 + e][c] = (_Float16)pB0;
        pbuf[w][16 + g * 4 + e][16 + c] = (_Float16)pB1;
        // register-direct attn stores: each inst = 4 rows x full 64B sectors
        __builtin_nontemporal_store(pA0, ab + (size_t)(g * 4 + e) * S_LEN);
        __builtin_nontemporal_store(pA1, ab + (size_t)(g * 4 + e) * S_LEN + 16);
        __builtin_nontemporal_store(pB0, ab + (size_t)(16 + g * 4 + e) * S_LEN);
        __builtin_nontemporal_store(pB1, ab + (size_t)(16 + g * 4 + e) * S_LEN + 16);
      }
      // wave-synchronous LDS (same wave wrote, same wave reads)
      half8 paA = *(const half8*)&pbuf[w][c][g * 8];
      half8 paB = *(const half8*)&pbuf[w][16 + c][g * 8];

      // PV: shared V fragments feed both row-tiles
#pragma unroll
      for (int nn = 0; nn < 4; nn++) {
        const _Float16* vp = Vb + (size_t)(nn * 16 + c) * S_LEN + kt * 32 + g * 8;
        half8 vb = *(const half8*)vp;
        ctxA[nn] = MFMA16x32(paA, vb, ctxA[nn]);
        ctxB[nn] = MFMA16x32(paB, vb, ctxB[nn]);
      }
    }
  }

  // ---------------- ctx combine across the two halves ----------------------
  __syncthreads();   // pbuf dead beyond here; cbuf aliases it
  if (half == 1) {
#pragma unroll
    for (int nn = 0; nn < 4; nn++) {
#pragma unroll
      for (int e = 0; e < 4; e++) {
        cbuf[tb][g * 4 + e][nn * 16 + c] = ctxA[nn][e];
        cbuf[tb][16 + g * 4 + e][nn * 16 + c] = ctxB[nn][e];
      }
    }
  }
  __syncthreads();
  if (half == 0) {
    float* cb = out + ((size_t)(bh * S_LEN + q0)) * DKV;
#pragma unroll
    for (int nn = 0; nn < 4; nn++) {
#pragma unroll
      for (int e = 0; e < 4; e++) {
        float vA = ctxA[nn][e] + cbuf[tb][g * 4 + e][nn * 16 + c];
        float vB = ctxB[nn][e] + cbuf[tb][16 + g * 4 + e][nn * 16 + c];
        __builtin_nontemporal_store(vA, cb + (size_t)(g * 4 + e) * DKV + nn * 16 + c);
        __builtin_nontemporal_store(vB, cb + (size_t)(16 + g * 4 + e) * DKV + nn * 16 + c);
      }
    }
  }
}

// ---------------------------------------------------------------------------
// Fallback (R1 kernel) if ws is too small.
// ---------------------------------------------------------------------------
__global__ __launch_bounds__(512, 1)
void attn_slow_kernel(const float* __restrict__ Q, const float* __restrict__ K,
                      const float* __restrict__ V, const void* __restrict__ maskv,
                      float* __restrict__ out, const int* __restrict__ flag) {
  __shared__ __align__(16) unsigned char smem[16 * 2056 * 2];
  __shared__ float redm[8][16];
  __shared__ float reds[8][16];
  _Float16 (*P)[2056] = (_Float16 (*)[2056])smem;

  const int bh = blockIdx.y;
  const int q0 = blockIdx.x << 4;
  const int tid = threadIdx.x;
  const int w = tid >> 6;
  const int lane = tid & 63;
  const int g = lane >> 4;
  const int c = lane & 15;
  const int k0 = w << 8;

  const bool mask_w = (*flag) != 0;
  const unsigned char* m8 = (const unsigned char*)maskv;
  const unsigned int* m32 = (const unsigned int*)maskv;

  const float* Qb = Q + ((size_t)bh * S_LEN + q0) * DKV;
  const float* Kb = K + (size_t)bh * S_LEN * DKV;
  const float* Vb = V + (size_t)bh * S_LEN * DKV;
  const size_t mbase = ((size_t)bh * S_LEN + q0) * S_LEN;
  float* ctx_out = out + ((size_t)bh * S_LEN + q0) * DKV;
  float* attn_out = out + CTX_ELEMS + mbase;

  half8 a0, a1;
  {
    const float* qrow = Qb + (size_t)c * DKV + g * 8;
    f32x4 x0 = *(const f32x4*)(qrow);
    f32x4 x1 = *(const f32x4*)(qrow + 4);
    f32x4 y0 = *(const f32x4*)(qrow + 32);
    f32x4 y1 = *(const f32x4*)(qrow + 36);
#pragma unroll
    for (int j = 0; j < 4; j++) {
      a0[j] = (_Float16)x0[j]; a0[4 + j] = (_Float16)x1[j];
      a1[j] = (_Float16)y0[j]; a1[4 + j] = (_Float16)y1[j];
    }
  }

  f32x4 acc[16];
#pragma unroll
  for (int n = 0; n < 16; n++) acc[n] = (f32x4)0.0f;
#pragma unroll
  for (int n = 0; n < 16; n++) {
    const float* kr = Kb + (size_t)(k0 + n * 16 + c) * DKV + g * 8;
    f32x4 x0 = *(const f32x4*)(kr);
    f32x4 x1 = *(const f32x4*)(kr + 4);
    f32x4 y0 = *(const f32x4*)(kr + 32);
    f32x4 y1 = *(const f32x4*)(kr + 36);
    half8 b0, b1;
#pragma unroll
    for (int j = 0; j < 4; j++) {
      b0[j] = (_Float16)x0[j]; b0[4 + j] = (_Float16)x1[j];
      b1[j] = (_Float16)y0[j]; b1[4 + j] = (_Float16)y1[j];
    }
    acc[n] = MFMA16x32(a0, b0, acc[n]);
    acc[n] = MFMA16x32(a1, b1, acc[n]);
  }

  float mx[4] = {-1e9f, -1e9f, -1e9f, -1e9f};
#pragma unroll
  for (int n = 0; n < 16; n++) {
    const int kc = k0 + n * 16 + c;
#pragma unroll
    for (int e = 0; e < 4; e++) {
      const size_t mi = mbase + (size_t)(g * 4 + e) * S_LEN + kc;
      bool masked;
      if (mask_w) masked = (__builtin_nontemporal_load(&m32[mi]) != 0u);
      else        masked = (__builtin_nontemporal_load(&m8[mi]) != 0);
      float s = masked ? -1e9f : acc[n][e] * 0.125f;
      acc[n][e] = s;
      mx[e] = fmaxf(mx[e], s);
    }
  }
#pragma unroll
  for (int off = 1; off < 16; off <<= 1) {
#pragma unroll
    for (int e = 0; e < 4; e++)
      mx[e] = fmaxf(mx[e], __shfl_xor(mx[e], off, 64));
  }
  if (c == 0) {
#pragma unroll
    for (int e = 0; e < 4; e++) redm[w][g * 4 + e] = mx[e];
  }
  __syncthreads();
  float m[4], sm[4];
#pragma unroll
  for (int e = 0; e < 4; e++) {
    float v = redm[0][g * 4 + e];
#pragma unroll
    for (int ww = 1; ww < 8; ww++) v = fmaxf(v, redm[ww][g * 4 + e]);
    m[e] = v;
    sm[e] = 0.0f;
  }
#pragma unroll
  for (int n = 0; n < 16; n++) {
#pragma unroll
    for (int e = 0; e < 4; e++) {
      float p = __expf(acc[n][e] - m[e]);
      acc[n][e] = p;
      sm[e] += p;
    }
  }
#pragma unroll
  for (int off = 1; off < 16; off <<= 1) {
#pragma unroll
    for (int e = 0; e < 4; e++) sm[e] += __shfl_xor(sm[e], off, 64);
  }
  if (c == 0) {
#pragma unroll
    for (int e = 0; e < 4; e++) reds[w][g * 4 + e] = sm[e];
  }
  __syncthreads();
  float inv[4];
#pragma unroll
  for (int e = 0; e < 4; e++) {
    float z = 0.0f;
#pragma unroll
    for (int ww = 0; ww < 8; ww++) z += reds[ww][g * 4 + e];
    inv[e] = 1.0f / z;
  }
#pragma unroll
  for (int n = 0; n < 16; n++) {
    const int kc = k0 + n * 16 + c;
#pragma unroll
    for (int e = 0; e < 4; e++) {
      float v = acc[n][e] * inv[e];
      __builtin_nontemporal_store(v, &attn_out[(size_t)(g * 4 + e) * S_LEN + kc]);
      P[g * 4 + e][kc] = (_Float16)v;
    }
  }
  __syncthreads();

  f32x4 ctx[4];
#pragma unroll
  for (int n = 0; n < 4; n++) ctx[n] = (f32x4)0.0f;
  for (int ks = 0; ks < 8; ks++) {
    const int kb = k0 + ks * 32;
    half8 pa = *(const half8*)&P[c][kb + g * 8];
#pragma unroll
    for (int n = 0; n < 4; n++) {
      const float* vp = Vb + (size_t)(kb + g * 8) * DKV + n * 16 + c;
      half8 vb;
#pragma unroll
      for (int j = 0; j < 8; j++) vb[j] = (_Float16)vp[(size_t)j * DKV];
      ctx[n] = MFMA16x32(pa, vb, ctx[n]);
    }
  }
  __syncthreads();

  float* red2 = (float*)smem;
#pragma unroll
  for (int n = 0; n < 4; n++) {
#pragma unroll
    for (int e = 0; e < 4; e++)
      red2[((w * 16) + g * 4 + e) * 64 + n * 16 + c] = ctx[n][e];
  }
  __syncthreads();
  for (int i = tid; i < 16 * 64; i += 512) {
    int q = i >> 6, d = i & 63;
    float ssum = 0.0f;
#pragma unroll
    for (int ww = 0; ww < 8; ww++) ssum += red2[((ww * 16) + q) * 64 + d];
    ctx_out[(size_t)q * DKV + d] = ssum;
  }
}

extern "C" void kernel_launch(void* const* d_in, const int* in_sizes, int n_in,
                              void* d_out, int out_size, void* d_ws, size_t ws_size,
                              hipStream_t stream) {
  (void)in_sizes; (void)n_in; (void)out_size;
  const float* Q = (const float*)d_in[0];
  const float* K = (const float*)d_in[1];
  const float* V = (const float*)d_in[2];
  const void* mask = d_in[3];

  const size_t HBYTES = (size_t)NBH * S_LEN * DKV * sizeof(_Float16);       // 8 MB
  const size_t BITBYTES = (size_t)NBH * S_LEN * (S_LEN / 32) * 4;           // 16 MB
  const size_t NEED = 256 + 3 * HBYTES + BITBYTES;

  int* flag = (int*)d_ws;
  hipLaunchKernelGGL(detect_mask_kernel, dim3(1), dim3(256), 0, stream,
                     (const unsigned char*)mask, flag);

  if (ws_size >= NEED) {
    _Float16* QH = (_Float16*)((char*)d_ws + 256);
    _Float16* KH = (_Float16*)((char*)d_ws + 256 + HBYTES);
    _Float16* VT = (_Float16*)((char*)d_ws + 256 + 2 * HBYTES);
    unsigned int* bits = (unsigned int*)((char*)d_ws + 256 + 3 * HBYTES);
    const int n4 = NBH * S_LEN * DKV / 4;
    hipLaunchKernelGGL(pack_mask_kernel, dim3(2048), dim3(256), 0, stream,
                       mask, flag, bits);
    hipLaunchKernelGGL(convert_f32_f16_kernel, dim3(n4 / 256), dim3(256), 0, stream,
                       Q, QH, 0.125f);
    hipLaunchKernelGGL(convert_f32_f16_kernel, dim3(n4 / 256), dim3(256), 0, stream,
                       K, KH, 1.0f);
    hipLaunchKernelGGL(transpose_v_kernel, dim3(S_LEN / 64, NBH), dim3(256), 0, stream, V, VT);
    hipLaunchKernelGGL(attn_v8_kernel, dim3(512), dim3(512), 0, stream,
                       QH, KH, VT, bits, (float*)d_out);
  } else {
    hipLaunchKernelGGL(attn_slow_kernel, dim3(128, 32), dim3(512), 0, stream,
                       Q, K, V, mask, (float*)d_out, flag);
  }
}

// Round 11
// 380.638 us; speedup vs baseline: 1.1815x; 1.1815x over previous
//
#include <hip/hip_runtime.h>
#include <hip/hip_fp16.h>

#define S_LEN 2048
#define DKV 64
#define NBH 32
#define CTX_ELEMS ((size_t)NBH * S_LEN * DKV)

using half8 = __attribute__((ext_vector_type(8))) _Float16;
using half4 = __attribute__((ext_vector_type(4))) _Float16;
using f32x4 = __attribute__((ext_vector_type(4))) float;
using u32x4 = __attribute__((ext_vector_type(4))) unsigned int;

#define MFMA16x32(a, b, c) __builtin_amdgcn_mfma_f32_16x16x32_f16((a), (b), (c), 0, 0, 0)

// ---------------------------------------------------------------------------
// Runtime mask-dtype detection (1-byte bool vs 4-byte int/float 0/1).
// ---------------------------------------------------------------------------
__global__ void detect_mask_kernel(const unsigned char* __restrict__ mask,
                                   int* __restrict__ flag) {
  __shared__ int nz0s, nzos;
  if (threadIdx.x == 0) { nz0s = 0; nzos = 0; }
  __syncthreads();
  int nz0 = 0, nzo = 0;
  for (int i = threadIdx.x; i < 65536; i += 256) {
    unsigned char b = mask[i];
    if (b) { if ((i & 3) == 0) nz0++; else nzo++; }
  }
  atomicAdd(&nz0s, nz0);
  atomicAdd(&nzos, nzo);
  __syncthreads();
  if (threadIdx.x == 0) *flag = (nz0s > 0 && nzos > 0) ? 0 : 1;
}

// ---------------------------------------------------------------------------
// Pack mask -> 1 bit per element. Bit f of dword bits[f>>5] = (mask[f] != 0).
// int32 path: 16B/lane coalesced loads, nibble -> dword via 3x shfl_xor OR
// within 8-lane groups. No LDS, no barriers (R10 lesson: keep 16B loads,
// drop the barrier pipeline).
// byte path: legacy LDS nibble path.
// ---------------------------------------------------------------------------
__global__ void pack_mask_kernel(const void* __restrict__ maskv,
                                 const int* __restrict__ flag,
                                 unsigned int* __restrict__ bits) {
  __shared__ unsigned char nib[256];
  const bool w4 = (*flag) != 0;
  const int tid = threadIdx.x;
  const unsigned int* m32 = (const unsigned int*)maskv;
  if (w4) {
    const int w = tid >> 6;
    const int lane = tid & 63;
    for (int it = 0; it < 64; ++it) {
      // wave w, iter it: elements [wb, wb+256)
      const size_t wb = ((size_t)blockIdx.x * 64 + it) * 1024 + (size_t)w * 256;
      u32x4 v = __builtin_nontemporal_load((const u32x4*)(m32 + wb + lane * 4));
      unsigned int x = ((v[0] ? 1u : 0u) | (v[1] ? 2u : 0u) |
                        (v[2] ? 4u : 0u) | (v[3] ? 8u : 0u)) << ((lane & 7) * 4);
      x |= __shfl_xor(x, 1, 64);
      x |= __shfl_xor(x, 2, 64);
      x |= __shfl_xor(x, 4, 64);
      if ((lane & 7) == 0)
        bits[(wb >> 5) + (lane >> 3)] = x;
    }
  } else {
    for (int it = 0; it < 64; ++it) {
      const size_t e0 = ((size_t)blockIdx.x * 64 + it) * 1024;
      const size_t ei = e0 + (size_t)tid * 4;
      unsigned int b = __builtin_nontemporal_load(m32 + (ei >> 2));
      unsigned int nv = ((b & 0xffu) ? 1u : 0u) | ((b & 0xff00u) ? 2u : 0u) |
                        ((b & 0xff0000u) ? 4u : 0u) | ((b & 0xff000000u) ? 8u : 0u);
      __syncthreads();
      nib[tid] = (unsigned char)nv;
      __syncthreads();
      if (tid < 32) {
        unsigned int dw = 0;
#pragma unroll
        for (int t = 0; t < 8; ++t)
          dw |= ((unsigned int)nib[tid * 8 + t]) << (t * 4);
        bits[(e0 >> 5) + tid] = dw;
      }
    }
  }
}

// ---------------------------------------------------------------------------
// fp32 -> fp16 elementwise with scale (Q gets 0.125 folded in, K gets 1.0).
// ---------------------------------------------------------------------------
__global__ void convert_f32_f16_kernel(const float* __restrict__ src,
                                       _Float16* __restrict__ dst, float scale) {
  size_t i = (size_t)blockIdx.x * blockDim.x + threadIdx.x;
  f32x4 v = *(const f32x4*)(src + i * 4);
  half4 h;
#pragma unroll
  for (int j = 0; j < 4; j++) h[j] = (_Float16)(v[j] * scale);
  *(half4*)(dst + i * 4) = h;
}

// ---------------------------------------------------------------------------
// V [bh][k][d] fp32 -> VT [bh][d][k] fp16.
// ---------------------------------------------------------------------------
__global__ void transpose_v_kernel(const float* __restrict__ V,
                                   _Float16* __restrict__ VT) {
  __shared__ _Float16 t[64][68];
  const int bh = blockIdx.y;
  const int k0 = blockIdx.x * 64;
  const float* Vb = V + ((size_t)bh * S_LEN + k0) * DKV;
#pragma unroll
  for (int it = 0; it < 4; it++) {
    int idx = threadIdx.x + it * 256;
    int kl = idx >> 4;
    int dq = (idx & 15) * 4;
    f32x4 v = *(const f32x4*)(Vb + (size_t)kl * DKV + dq);
#pragma unroll
    for (int j = 0; j < 4; j++) t[kl][dq + j] = (_Float16)v[j];
  }
  __syncthreads();
  _Float16* VTb = VT + (size_t)bh * DKV * S_LEN;
#pragma unroll
  for (int it = 0; it < 4; it++) {
    int idx = threadIdx.x + it * 256;
    int d = idx >> 4;
    int kq = (idx & 15) * 4;
    half4 h;
#pragma unroll
    for (int j = 0; j < 4; j++) h[j] = t[kq + j][d];
    *(half4*)(VTb + (size_t)d * S_LEN + k0 + kq) = h;
  }
}

// ---------------------------------------------------------------------------
// Main attention v9 (= proven v7 structure; only change: Q prescaled by
// 0.125 in the convert, so no in-loop scale). Each wave owns a 32-row
// q-tile (2 MFMA row-tiles A,B sharing K and V fragments). 8 waves =
// 4 q32-tiles x 2 k-halves; no-max softmax; grid 512; lb(512,2) -> VGPR 128.
// ---------------------------------------------------------------------------
__global__ __launch_bounds__(512, 2)
void attn_v9_kernel(const _Float16* __restrict__ QH, const _Float16* __restrict__ KH,
                    const _Float16* __restrict__ VT, const unsigned int* __restrict__ bits,
                    float* __restrict__ out) {
  __shared__ __align__(16) _Float16 pbuf[8][32][40];  // per-wave P slice [32 q][32 k]
  __shared__ float zbuf[4][2][32];
  __shared__ __align__(16) float cbuf[4][32][64];

  const int tid = threadIdx.x;
  const int w = tid >> 6;
  const int lane = tid & 63;
  const int g = lane >> 4;
  const int c = lane & 15;
  const int tb = w >> 1;         // q32-tile within block (0..3)
  const int half = w & 1;        // k-half: kt4 in [half*8, half*8+8)

  // XCD-chunked swizzle (512 % 8 == 0 -> bijective).
  const int phys = blockIdx.x;
  const int orig = (phys & 7) * 64 + (phys >> 3);
  const int tile = orig * 4 + tb;          // 0..2047 (q32 tiles)
  const int bh = tile >> 6;
  const int q0 = (tile & 63) << 5;

  // Q fragments for row-tiles A (q0..q0+15) and B (q0+16..q0+31); Q prescaled.
  const _Float16* qpA = QH + ((size_t)(bh * S_LEN + q0 + c)) * DKV + g * 8;
  const half8 aA0 = *(const half8*)qpA;
  const half8 aA1 = *(const half8*)(qpA + 32);
  const _Float16* qpB = qpA + 16 * DKV;
  const half8 aB0 = *(const half8*)qpB;
  const half8 aB1 = *(const half8*)(qpB + 32);

  const _Float16* Kb = KH + (size_t)bh * S_LEN * DKV;
  const unsigned int* bq = bits + ((size_t)(bh * S_LEN + q0)) * (S_LEN / 32);

  float ZsA[4] = {0.0f, 0.0f, 0.0f, 0.0f};
  float ZsB[4] = {0.0f, 0.0f, 0.0f, 0.0f};

  // ---------------- pass 1: Z = sum over unmasked exp(s) -------------------
  for (int kt4 = half * 8; kt4 < half * 8 + 8; ++kt4) {
#pragma unroll
    for (int sub = 0; sub < 4; ++sub) {
      const int kt = kt4 * 4 + sub;
      unsigned int mwA[4], mwB[4];
#pragma unroll
      for (int e = 0; e < 4; e++) {
        mwA[e] = bq[(size_t)(g * 4 + e) * (S_LEN / 32) + kt];
        mwB[e] = bq[(size_t)(16 + g * 4 + e) * (S_LEN / 32) + kt];
      }
      const _Float16* kp = Kb + ((size_t)(kt * 32 + c)) * DKV + g * 8;
      half8 k00 = *(const half8*)kp;
      half8 k01 = *(const half8*)(kp + 32);
      half8 k10 = *(const half8*)(kp + 16 * DKV);
      half8 k11 = *(const half8*)(kp + 16 * DKV + 32);
      f32x4 acA0 = (f32x4)0.0f, acA1 = (f32x4)0.0f;
      f32x4 acB0 = (f32x4)0.0f, acB1 = (f32x4)0.0f;
      acA0 = MFMA16x32(aA0, k00, acA0);
      acA0 = MFMA16x32(aA1, k01, acA0);
      acB0 = MFMA16x32(aB0, k00, acB0);
      acB0 = MFMA16x32(aB1, k01, acB0);
      acA1 = MFMA16x32(aA0, k10, acA1);
      acA1 = MFMA16x32(aA1, k11, acA1);
      acB1 = MFMA16x32(aB0, k10, acB1);
      acB1 = MFMA16x32(aB1, k11, acB1);
#pragma unroll
      for (int e = 0; e < 4; e++) {
        float pA0 = ((mwA[e] >> c) & 1u) ? 0.0f : __expf(acA0[e]);
        float pA1 = ((mwA[e] >> (16 + c)) & 1u) ? 0.0f : __expf(acA1[e]);
        float pB0 = ((mwB[e] >> c) & 1u) ? 0.0f : __expf(acB0[e]);
        float pB1 = ((mwB[e] >> (16 + c)) & 1u) ? 0.0f : __expf(acB1[e]);
        ZsA[e] += pA0 + pA1;
        ZsB[e] += pB0 + pB1;
      }
    }
  }
  // merge the 16 c-lanes sharing each row
#pragma unroll
  for (int off = 1; off < 16; off <<= 1) {
#pragma unroll
    for (int e = 0; e < 4; e++) {
      ZsA[e] += __shfl_xor(ZsA[e], off, 64);
      ZsB[e] += __shfl_xor(ZsB[e], off, 64);
    }
  }
  if (c == 0) {
#pragma unroll
    for (int e = 0; e < 4; e++) {
      zbuf[tb][half][g * 4 + e] = ZsA[e];
      zbuf[tb][half][16 + g * 4 + e] = ZsB[e];
    }
  }
  __syncthreads();
  float lZA[4], lZB[4];
#pragma unroll
  for (int e = 0; e < 4; e++) {
    lZA[e] = __logf(zbuf[tb][0][g * 4 + e] + zbuf[tb][1][g * 4 + e]);
    lZB[e] = __logf(zbuf[tb][0][16 + g * 4 + e] + zbuf[tb][1][16 + g * 4 + e]);
  }

  // ---------------- pass 2: attn = exp(s - lnZ), PV ------------------------
  f32x4 ctxA[4], ctxB[4];
#pragma unroll
  for (int nn = 0; nn < 4; nn++) { ctxA[nn] = (f32x4)0.0f; ctxB[nn] = (f32x4)0.0f; }

  const _Float16* Vb = VT + (size_t)bh * DKV * S_LEN;
  float* attn_base = out + CTX_ELEMS + ((size_t)(bh * S_LEN + q0)) * S_LEN;

  for (int kt4 = half * 8; kt4 < half * 8 + 8; ++kt4) {
#pragma unroll
    for (int sub = 0; sub < 4; ++sub) {
      const int kt = kt4 * 4 + sub;
      unsigned int mwA[4], mwB[4];
#pragma unroll
      for (int e = 0; e < 4; e++) {
        mwA[e] = bq[(size_t)(g * 4 + e) * (S_LEN / 32) + kt];
        mwB[e] = bq[(size_t)(16 + g * 4 + e) * (S_LEN / 32) + kt];
      }
      const _Float16* kp = Kb + ((size_t)(kt * 32 + c)) * DKV + g * 8;
      half8 k00 = *(const half8*)kp;
      half8 k01 = *(const half8*)(kp + 32);
      half8 k10 = *(const half8*)(kp + 16 * DKV);
      half8 k11 = *(const half8*)(kp + 16 * DKV + 32);
      f32x4 acA0 = (f32x4)0.0f, acA1 = (f32x4)0.0f;
      f32x4 acB0 = (f32x4)0.0f, acB1 = (f32x4)0.0f;
      acA0 = MFMA16x32(aA0, k00, acA0);
      acA0 = MFMA16x32(aA1, k01, acA0);
      acB0 = MFMA16x32(aB0, k00, acB0);
      acB0 = MFMA16x32(aB1, k01, acB0);
      acA1 = MFMA16x32(aA0, k10, acA1);
      acA1 = MFMA16x32(aA1, k11, acA1);
      acB1 = MFMA16x32(aB0, k10, acB1);
      acB1 = MFMA16x32(aB1, k11, acB1);
#pragma unroll
      for (int e = 0; e < 4; e++) {
        float pA0 = ((mwA[e] >> c) & 1u) ? 0.0f : __expf(acA0[e] - lZA[e]);
        float pA1 = ((mwA[e] >> (16 + c)) & 1u) ? 0.0f : __expf(acA1[e] - lZA[e]);
        float pB0 = ((mwB[e] >> c) & 1u) ? 0.0f : __expf(acB0[e] - lZB[e]);
        float pB1 = ((mwB[e] >> (16 + c)) & 1u) ? 0.0f : __expf(acB1[e] - lZB[e]);
        pbuf[w][g * 4 + e][c] = (_Float16)pA0;
        pbuf[w][g * 4 + e][16 + c] = (_Float16)pA1;
        pbuf[w][16 + g * 4 + e][c] = (_Float16)pB0;
        pbuf[w][16 + g * 4 + e][16 + c] = (_Float16)pB1;
      }
      // wave-synchronous LDS (same wave wrote, same wave reads)
      half8 paA = *(const half8*)&pbuf[w][c][g * 8];
      half8 paB = *(const half8*)&pbuf[w][16 + c][g * 8];

      // attn stores: 4 instructions x 1 KB contiguous (8 rows x 128 B each)
#pragma unroll
      for (int s = 0; s < 4; s++) {
        const int r = (lane >> 3) + s * 8;
        const int c4 = (lane & 7) * 4;
        half4 h = *(const half4*)&pbuf[w][r][c4];
        f32x4 o;
#pragma unroll
        for (int j = 0; j < 4; j++) o[j] = (float)h[j];
        __builtin_nontemporal_store(o,
            (f32x4*)(attn_base + (size_t)r * S_LEN + kt * 32 + c4));
      }
      // PV: shared V fragments feed both row-tiles
#pragma unroll
      for (int nn = 0; nn < 4; nn++) {
        const _Float16* vp = Vb + (size_t)(nn * 16 + c) * S_LEN + kt * 32 + g * 8;
        half8 vb = *(const half8*)vp;
        ctxA[nn] = MFMA16x32(paA, vb, ctxA[nn]);
        ctxB[nn] = MFMA16x32(paB, vb, ctxB[nn]);
      }
    }
  }

  // ---------------- ctx combine across the two halves ----------------------
  __syncthreads();
  if (half == 1) {
#pragma unroll
    for (int nn = 0; nn < 4; nn++) {
#pragma unroll
      for (int e = 0; e < 4; e++) {
        cbuf[tb][g * 4 + e][nn * 16 + c] = ctxA[nn][e];
        cbuf[tb][16 + g * 4 + e][nn * 16 + c] = ctxB[nn][e];
      }
    }
  }
  __syncthreads();
  if (half == 0) {
    float* cb = out + ((size_t)(bh * S_LEN + q0)) * DKV;
#pragma unroll
    for (int nn = 0; nn < 4; nn++) {
#pragma unroll
      for (int e = 0; e < 4; e++) {
        float vA = ctxA[nn][e] + cbuf[tb][g * 4 + e][nn * 16 + c];
        float vB = ctxB[nn][e] + cbuf[tb][16 + g * 4 + e][nn * 16 + c];
        __builtin_nontemporal_store(vA, cb + (size_t)(g * 4 + e) * DKV + nn * 16 + c);
        __builtin_nontemporal_store(vB, cb + (size_t)(16 + g * 4 + e) * DKV + nn * 16 + c);
      }
    }
  }
}

// ---------------------------------------------------------------------------
// Fallback (R1 kernel) if ws is too small.
// ---------------------------------------------------------------------------
__global__ __launch_bounds__(512, 1)
void attn_slow_kernel(const float* __restrict__ Q, const float* __restrict__ K,
                      const float* __restrict__ V, const void* __restrict__ maskv,
                      float* __restrict__ out, const int* __restrict__ flag) {
  __shared__ __align__(16) unsigned char smem[16 * 2056 * 2];
  __shared__ float redm[8][16];
  __shared__ float reds[8][16];
  _Float16 (*P)[2056] = (_Float16 (*)[2056])smem;

  const int bh = blockIdx.y;
  const int q0 = blockIdx.x << 4;
  const int tid = threadIdx.x;
  const int w = tid >> 6;
  const int lane = tid & 63;
  const int g = lane >> 4;
  const int c = lane & 15;
  const int k0 = w << 8;

  const bool mask_w = (*flag) != 0;
  const unsigned char* m8 = (const unsigned char*)maskv;
  const unsigned int* m32 = (const unsigned int*)maskv;

  const float* Qb = Q + ((size_t)bh * S_LEN + q0) * DKV;
  const float* Kb = K + (size_t)bh * S_LEN * DKV;
  const float* Vb = V + (size_t)bh * S_LEN * DKV;
  const size_t mbase = ((size_t)bh * S_LEN + q0) * S_LEN;
  float* ctx_out = out + ((size_t)bh * S_LEN + q0) * DKV;
  float* attn_out = out + CTX_ELEMS + mbase;

  half8 a0, a1;
  {
    const float* qrow = Qb + (size_t)c * DKV + g * 8;
    f32x4 x0 = *(const f32x4*)(qrow);
    f32x4 x1 = *(const f32x4*)(qrow + 4);
    f32x4 y0 = *(const f32x4*)(qrow + 32);
    f32x4 y1 = *(const f32x4*)(qrow + 36);
#pragma unroll
    for (int j = 0; j < 4; j++) {
      a0[j] = (_Float16)x0[j]; a0[4 + j] = (_Float16)x1[j];
      a1[j] = (_Float16)y0[j]; a1[4 + j] = (_Float16)y1[j];
    }
  }

  f32x4 acc[16];
#pragma unroll
  for (int n = 0; n < 16; n++) acc[n] = (f32x4)0.0f;
#pragma unroll
  for (int n = 0; n < 16; n++) {
    const float* kr = Kb + (size_t)(k0 + n * 16 + c) * DKV + g * 8;
    f32x4 x0 = *(const f32x4*)(kr);
    f32x4 x1 = *(const f32x4*)(kr + 4);
    f32x4 y0 = *(const f32x4*)(kr + 32);
    f32x4 y1 = *(const f32x4*)(kr + 36);
    half8 b0, b1;
#pragma unroll
    for (int j = 0; j < 4; j++) {
      b0[j] = (_Float16)x0[j]; b0[4 + j] = (_Float16)x1[j];
      b1[j] = (_Float16)y0[j]; b1[4 + j] = (_Float16)y1[j];
    }
    acc[n] = MFMA16x32(a0, b0, acc[n]);
    acc[n] = MFMA16x32(a1, b1, acc[n]);
  }

  float mx[4] = {-1e9f, -1e9f, -1e9f, -1e9f};
#pragma unroll
  for (int n = 0; n < 16; n++) {
    const int kc = k0 + n * 16 + c;
#pragma unroll
    for (int e = 0; e < 4; e++) {
      const size_t mi = mbase + (size_t)(g * 4 + e) * S_LEN + kc;
      bool masked;
      if (mask_w) masked = (__builtin_nontemporal_load(&m32[mi]) != 0u);
      else        masked = (__builtin_nontemporal_load(&m8[mi]) != 0);
      float s = masked ? -1e9f : acc[n][e] * 0.125f;
      acc[n][e] = s;
      mx[e] = fmaxf(mx[e], s);
    }
  }
#pragma unroll
  for (int off = 1; off < 16; off <<= 1) {
#pragma unroll
    for (int e = 0; e < 4; e++)
      mx[e] = fmaxf(mx[e], __shfl_xor(mx[e], off, 64));
  }
  if (c == 0) {
#pragma unroll
    for (int e = 0; e < 4; e++) redm[w][g * 4 + e] = mx[e];
  }
  __syncthreads();
  float m[4], sm[4];
#pragma unroll
  for (int e = 0; e < 4; e++) {
    float v = redm[0][g * 4 + e];
#pragma unroll
    for (int ww = 1; ww < 8; ww++) v = fmaxf(v, redm[ww][g * 4 + e]);
    m[e] = v;
    sm[e] = 0.0f;
  }
#pragma unroll
  for (int n = 0; n < 16; n++) {
#pragma unroll
    for (int e = 0; e < 4; e++) {
      float p = __expf(acc[n][e] - m[e]);
      acc[n][e] = p;
      sm[e] += p;
    }
  }
#pragma unroll
  for (int off = 1; off < 16; off <<= 1) {
#pragma unroll
    for (int e = 0; e < 4; e++) sm[e] += __shfl_xor(sm[e], off, 64);
  }
  if (c == 0) {
#pragma unroll
    for (int e = 0; e < 4; e++) reds[w][g * 4 + e] = sm[e];
  }
  __syncthreads();
  float inv[4];
#pragma unroll
  for (int e = 0; e < 4; e++) {
    float z = 0.0f;
#pragma unroll
    for (int ww = 0; ww < 8; ww++) z += reds[ww][g * 4 + e];
    inv[e] = 1.0f / z;
  }
#pragma unroll
  for (int n = 0; n < 16; n++) {
    const int kc = k0 + n * 16 + c;
#pragma unroll
    for (int e = 0; e < 4; e++) {
      float v = acc[n][e] * inv[e];
      __builtin_nontemporal_store(v, &attn_out[(size_t)(g * 4 + e) * S_LEN + kc]);
      P[g * 4 + e][kc] = (_Float16)v;
    }
  }
  __syncthreads();

  f32x4 ctx[4];
#pragma unroll
  for (int n = 0; n < 4; n++) ctx[n] = (f32x4)0.0f;
  for (int ks = 0; ks < 8; ks++) {
    const int kb = k0 + ks * 32;
    half8 pa = *(const half8*)&P[c][kb + g * 8];
#pragma unroll
    for (int n = 0; n < 4; n++) {
      const float* vp = Vb + (size_t)(kb + g * 8) * DKV + n * 16 + c;
      half8 vb;
#pragma unroll
      for (int j = 0; j < 8; j++) vb[j] = (_Float16)vp[(size_t)j * DKV];
      ctx[n] = MFMA16x32(pa, vb, ctx[n]);
    }
  }
  __syncthreads();

  float* red2 = (float*)smem;
#pragma unroll
  for (int n = 0; n < 4; n++) {
#pragma unroll
    for (int e = 0; e < 4; e++)
      red2[((w * 16) + g * 4 + e) * 64 + n * 16 + c] = ctx[n][e];
  }
  __syncthreads();
  for (int i = tid; i < 16 * 64; i += 512) {
    int q = i >> 6, d = i & 63;
    float ssum = 0.0f;
#pragma unroll
    for (int ww = 0; ww < 8; ww++) ssum += red2[((ww * 16) + q) * 64 + d];
    ctx_out[(size_t)q * DKV + d] = ssum;
  }
}

extern "C" void kernel_launch(void* const* d_in, const int* in_sizes, int n_in,
                              void* d_out, int out_size, void* d_ws, size_t ws_size,
                              hipStream_t stream) {
  (void)in_sizes; (void)n_in; (void)out_size;
  const float* Q = (const float*)d_in[0];
  const float* K = (const float*)d_in[1];
  const float* V = (const float*)d_in[2];
  const void* mask = d_in[3];

  const size_t HBYTES = (size_t)NBH * S_LEN * DKV * sizeof(_Float16);       // 8 MB
  const size_t BITBYTES = (size_t)NBH * S_LEN * (S_LEN / 32) * 4;           // 16 MB
  const size_t NEED = 256 + 3 * HBYTES + BITBYTES;

  int* flag = (int*)d_ws;
  hipLaunchKernelGGL(detect_mask_kernel, dim3(1), dim3(256), 0, stream,
                     (const unsigned char*)mask, flag);

  if (ws_size >= NEED) {
    _Float16* QH = (_Float16*)((char*)d_ws + 256);
    _Float16* KH = (_Float16*)((char*)d_ws + 256 + HBYTES);
    _Float16* VT = (_Float16*)((char*)d_ws + 256 + 2 * HBYTES);
    unsigned int* bits = (unsigned int*)((char*)d_ws + 256 + 3 * HBYTES);
    const int n4 = NBH * S_LEN * DKV / 4;
    hipLaunchKernelGGL(pack_mask_kernel, dim3(2048), dim3(256), 0, stream,
                       mask, flag, bits);
    hipLaunchKernelGGL(convert_f32_f16_kernel, dim3(n4 / 256), dim3(256), 0, stream,
                       Q, QH, 0.125f);
    hipLaunchKernelGGL(convert_f32_f16_kernel, dim3(n4 / 256), dim3(256), 0, stream,
                       K, KH, 1.0f);
    hipLaunchKernelGGL(transpose_v_kernel, dim3(S_LEN / 64, NBH), dim3(256), 0, stream, V, VT);
    hipLaunchKernelGGL(attn_v9_kernel, dim3(512), dim3(512), 0, stream,
                       QH, KH, VT, bits, (float*)d_out);
  } else {
    hipLaunchKernelGGL(attn_slow_kernel, dim3(128, 32), dim3(512), 0, stream,
                       Q, K, V, mask, (float*)d_out, flag);
  }
}

// Round 12
// 351.169 us; speedup vs baseline: 1.2806x; 1.0839x over previous
//
#include <hip/hip_runtime.h>
#include <hip/hip_fp16.h>

#define S_LEN 2048
#define DKV 64
#define NBH 32
#define CTX_ELEMS ((size_t)NBH * S_LEN * DKV)

using half8 = __attribute__((ext_vector_type(8))) _Float16;
using half4 = __attribute__((ext_vector_type(4))) _Float16;
using f32x4 = __attribute__((ext_vector_type(4))) float;
using u32x4 = __attribute__((ext_vector_type(4))) unsigned int;

#define MFMA16x32(a, b, c) __builtin_amdgcn_mfma_f32_16x16x32_f16((a), (b), (c), 0, 0, 0)

// ---------------------------------------------------------------------------
// Runtime mask-dtype detection (1-byte bool vs 4-byte int/float 0/1).
// Vectorized: 512 threads, u32x4 loads over the first 128 KB.
// ---------------------------------------------------------------------------
__global__ void detect_mask_kernel(const unsigned char* __restrict__ mask,
                                   int* __restrict__ flag) {
  __shared__ int nz0s, nzos;
  if (threadIdx.x == 0) { nz0s = 0; nzos = 0; }
  __syncthreads();
  const u32x4* m = (const u32x4*)mask;
  unsigned int a0 = 0, ao = 0;
  for (int i = threadIdx.x; i < 8192; i += 512) {
    u32x4 v = m[i];
#pragma unroll
    for (int j = 0; j < 4; j++) {
      a0 |= v[j] & 0xffu;
      ao |= v[j] & 0xffffff00u;
    }
  }
  if (a0) atomicAdd(&nz0s, 1);
  if (ao) atomicAdd(&nzos, 1);
  __syncthreads();
  if (threadIdx.x == 0) *flag = (nz0s > 0 && nzos > 0) ? 0 : 1;
}

// ---------------------------------------------------------------------------
// Pack mask -> 1 bit per element. Bit f of dword bits[f>>5] = (mask[f] != 0).
// int32 path: 16B/lane coalesced loads, nibble -> dword via 3x shfl_xor OR.
// ---------------------------------------------------------------------------
__global__ void pack_mask_kernel(const void* __restrict__ maskv,
                                 const int* __restrict__ flag,
                                 unsigned int* __restrict__ bits) {
  __shared__ unsigned char nib[256];
  const bool w4 = (*flag) != 0;
  const int tid = threadIdx.x;
  const unsigned int* m32 = (const unsigned int*)maskv;
  if (w4) {
    const int w = tid >> 6;
    const int lane = tid & 63;
    for (int it = 0; it < 64; ++it) {
      const size_t wb = ((size_t)blockIdx.x * 64 + it) * 1024 + (size_t)w * 256;
      u32x4 v = __builtin_nontemporal_load((const u32x4*)(m32 + wb + lane * 4));
      unsigned int x = ((v[0] ? 1u : 0u) | (v[1] ? 2u : 0u) |
                        (v[2] ? 4u : 0u) | (v[3] ? 8u : 0u)) << ((lane & 7) * 4);
      x |= __shfl_xor(x, 1, 64);
      x |= __shfl_xor(x, 2, 64);
      x |= __shfl_xor(x, 4, 64);
      if ((lane & 7) == 0)
        bits[(wb >> 5) + (lane >> 3)] = x;
    }
  } else {
    for (int it = 0; it < 64; ++it) {
      const size_t e0 = ((size_t)blockIdx.x * 64 + it) * 1024;
      const size_t ei = e0 + (size_t)tid * 4;
      unsigned int b = __builtin_nontemporal_load(m32 + (ei >> 2));
      unsigned int nv = ((b & 0xffu) ? 1u : 0u) | ((b & 0xff00u) ? 2u : 0u) |
                        ((b & 0xff0000u) ? 4u : 0u) | ((b & 0xff000000u) ? 8u : 0u);
      __syncthreads();
      nib[tid] = (unsigned char)nv;
      __syncthreads();
      if (tid < 32) {
        unsigned int dw = 0;
#pragma unroll
        for (int t = 0; t < 8; ++t)
          dw |= ((unsigned int)nib[tid * 8 + t]) << (t * 4);
        bits[(e0 >> 5) + tid] = dw;
      }
    }
  }
}

// ---------------------------------------------------------------------------
// fp32 -> fp16 elementwise with scale (Q gets 0.125 folded in, K gets 1.0).
// ---------------------------------------------------------------------------
__global__ void convert_f32_f16_kernel(const float* __restrict__ src,
                                       _Float16* __restrict__ dst, float scale) {
  size_t i = (size_t)blockIdx.x * blockDim.x + threadIdx.x;
  f32x4 v = *(const f32x4*)(src + i * 4);
  half4 h;
#pragma unroll
  for (int j = 0; j < 4; j++) h[j] = (_Float16)(v[j] * scale);
  *(half4*)(dst + i * 4) = h;
}

// ---------------------------------------------------------------------------
// V [bh][k][d] fp32 -> VT [bh][d][k] fp16.
// ---------------------------------------------------------------------------
__global__ void transpose_v_kernel(const float* __restrict__ V,
                                   _Float16* __restrict__ VT) {
  __shared__ _Float16 t[64][68];
  const int bh = blockIdx.y;
  const int k0 = blockIdx.x * 64;
  const float* Vb = V + ((size_t)bh * S_LEN + k0) * DKV;
#pragma unroll
  for (int it = 0; it < 4; it++) {
    int idx = threadIdx.x + it * 256;
    int kl = idx >> 4;
    int dq = (idx & 15) * 4;
    f32x4 v = *(const f32x4*)(Vb + (size_t)kl * DKV + dq);
#pragma unroll
    for (int j = 0; j < 4; j++) t[kl][dq + j] = (_Float16)v[j];
  }
  __syncthreads();
  _Float16* VTb = VT + (size_t)bh * DKV * S_LEN;
#pragma unroll
  for (int it = 0; it < 4; it++) {
    int idx = threadIdx.x + it * 256;
    int d = idx >> 4;
    int kq = (idx & 15) * 4;
    half4 h;
#pragma unroll
    for (int j = 0; j < 4; j++) h[j] = t[kq + j][d];
    *(half4*)(VTb + (size_t)d * S_LEN + k0 + kq) = h;
  }
}

// ---------------------------------------------------------------------------
// Main attention v10 = v9 + explicit 1-sub-lookahead K-fragment pipeline
// (double-buffered frag sets a/b; loads for sub s+1 issue before sub s's
// exp/store/PV block, hiding ~200cyc L2 latency under ~60-90 instructions).
// Each wave owns a 32-row q-tile; 8 waves = 4 q32-tiles x 2 k-halves;
// no-max softmax; grid 512; lb(512,2) -> VGPR cap 128.
// ---------------------------------------------------------------------------
#define LOADF(S, KT) { \
  const _Float16* kp_ = Kb + ((size_t)((KT) * 32 + c)) * DKV + g * 8; \
  k00##S = *(const half8*)kp_; \
  k01##S = *(const half8*)(kp_ + 32); \
  k10##S = *(const half8*)(kp_ + 16 * DKV); \
  k11##S = *(const half8*)(kp_ + 16 * DKV + 32); }

#define P1SUB(KT, S) { \
  unsigned int mwA[4], mwB[4]; \
  _Pragma("unroll") for (int e = 0; e < 4; e++) { \
    mwA[e] = bq[(size_t)(g * 4 + e) * (S_LEN / 32) + (KT)]; \
    mwB[e] = bq[(size_t)(16 + g * 4 + e) * (S_LEN / 32) + (KT)]; } \
  f32x4 acA0 = (f32x4)0.0f, acA1 = (f32x4)0.0f; \
  f32x4 acB0 = (f32x4)0.0f, acB1 = (f32x4)0.0f; \
  acA0 = MFMA16x32(aA0, k00##S, acA0); \
  acA0 = MFMA16x32(aA1, k01##S, acA0); \
  acB0 = MFMA16x32(aB0, k00##S, acB0); \
  acB0 = MFMA16x32(aB1, k01##S, acB0); \
  acA1 = MFMA16x32(aA0, k10##S, acA1); \
  acA1 = MFMA16x32(aA1, k11##S, acA1); \
  acB1 = MFMA16x32(aB0, k10##S, acB1); \
  acB1 = MFMA16x32(aB1, k11##S, acB1); \
  _Pragma("unroll") for (int e = 0; e < 4; e++) { \
    float pA0 = ((mwA[e] >> c) & 1u) ? 0.0f : __expf(acA0[e]); \
    float pA1 = ((mwA[e] >> (16 + c)) & 1u) ? 0.0f : __expf(acA1[e]); \
    float pB0 = ((mwB[e] >> c) & 1u) ? 0.0f : __expf(acB0[e]); \
    float pB1 = ((mwB[e] >> (16 + c)) & 1u) ? 0.0f : __expf(acB1[e]); \
    ZsA[e] += pA0 + pA1; \
    ZsB[e] += pB0 + pB1; } }

#define P2SUB(KT, S) { \
  unsigned int mwA[4], mwB[4]; \
  _Pragma("unroll") for (int e = 0; e < 4; e++) { \
    mwA[e] = bq[(size_t)(g * 4 + e) * (S_LEN / 32) + (KT)]; \
    mwB[e] = bq[(size_t)(16 + g * 4 + e) * (S_LEN / 32) + (KT)]; } \
  /* V loads issued early: latency hides under exp/LDS below */ \
  half8 vb0 = *(const half8*)(Vb + (size_t)(0 * 16 + c) * S_LEN + (KT) * 32 + g * 8); \
  half8 vb1 = *(const half8*)(Vb + (size_t)(1 * 16 + c) * S_LEN + (KT) * 32 + g * 8); \
  half8 vb2 = *(const half8*)(Vb + (size_t)(2 * 16 + c) * S_LEN + (KT) * 32 + g * 8); \
  half8 vb3 = *(const half8*)(Vb + (size_t)(3 * 16 + c) * S_LEN + (KT) * 32 + g * 8); \
  f32x4 acA0 = (f32x4)0.0f, acA1 = (f32x4)0.0f; \
  f32x4 acB0 = (f32x4)0.0f, acB1 = (f32x4)0.0f; \
  acA0 = MFMA16x32(aA0, k00##S, acA0); \
  acA0 = MFMA16x32(aA1, k01##S, acA0); \
  acB0 = MFMA16x32(aB0, k00##S, acB0); \
  acB0 = MFMA16x32(aB1, k01##S, acB0); \
  acA1 = MFMA16x32(aA0, k10##S, acA1); \
  acA1 = MFMA16x32(aA1, k11##S, acA1); \
  acB1 = MFMA16x32(aB0, k10##S, acB1); \
  acB1 = MFMA16x32(aB1, k11##S, acB1); \
  _Pragma("unroll") for (int e = 0; e < 4; e++) { \
    float pA0 = ((mwA[e] >> c) & 1u) ? 0.0f : __expf(acA0[e] - lZA[e]); \
    float pA1 = ((mwA[e] >> (16 + c)) & 1u) ? 0.0f : __expf(acA1[e] - lZA[e]); \
    float pB0 = ((mwB[e] >> c) & 1u) ? 0.0f : __expf(acB0[e] - lZB[e]); \
    float pB1 = ((mwB[e] >> (16 + c)) & 1u) ? 0.0f : __expf(acB1[e] - lZB[e]); \
    pbuf[w][g * 4 + e][c] = (_Float16)pA0; \
    pbuf[w][g * 4 + e][16 + c] = (_Float16)pA1; \
    pbuf[w][16 + g * 4 + e][c] = (_Float16)pB0; \
    pbuf[w][16 + g * 4 + e][16 + c] = (_Float16)pB1; } \
  half8 paA = *(const half8*)&pbuf[w][c][g * 8]; \
  half8 paB = *(const half8*)&pbuf[w][16 + c][g * 8]; \
  _Pragma("unroll") for (int s = 0; s < 4; s++) { \
    const int r = (lane >> 3) + s * 8; \
    const int c4 = (lane & 7) * 4; \
    half4 h = *(const half4*)&pbuf[w][r][c4]; \
    f32x4 o; \
    _Pragma("unroll") for (int j = 0; j < 4; j++) o[j] = (float)h[j]; \
    __builtin_nontemporal_store(o, \
        (f32x4*)(attn_base + (size_t)r * S_LEN + (KT) * 32 + c4)); } \
  ctxA[0] = MFMA16x32(paA, vb0, ctxA[0]); \
  ctxB[0] = MFMA16x32(paB, vb0, ctxB[0]); \
  ctxA[1] = MFMA16x32(paA, vb1, ctxA[1]); \
  ctxB[1] = MFMA16x32(paB, vb1, ctxB[1]); \
  ctxA[2] = MFMA16x32(paA, vb2, ctxA[2]); \
  ctxB[2] = MFMA16x32(paB, vb2, ctxB[2]); \
  ctxA[3] = MFMA16x32(paA, vb3, ctxA[3]); \
  ctxB[3] = MFMA16x32(paB, vb3, ctxB[3]); }

__global__ __launch_bounds__(512, 2)
void attn_v10_kernel(const _Float16* __restrict__ QH, const _Float16* __restrict__ KH,
                     const _Float16* __restrict__ VT, const unsigned int* __restrict__ bits,
                     float* __restrict__ out) {
  __shared__ __align__(16) _Float16 pbuf[8][32][40];
  __shared__ float zbuf[4][2][32];
  __shared__ __align__(16) float cbuf[4][32][64];

  const int tid = threadIdx.x;
  const int w = tid >> 6;
  const int lane = tid & 63;
  const int g = lane >> 4;
  const int c = lane & 15;
  const int tb = w >> 1;
  const int half = w & 1;

  // XCD-chunked swizzle (512 % 8 == 0 -> bijective).
  const int phys = blockIdx.x;
  const int orig = (phys & 7) * 64 + (phys >> 3);
  const int tile = orig * 4 + tb;
  const int bh = tile >> 6;
  const int q0 = (tile & 63) << 5;

  const _Float16* qpA = QH + ((size_t)(bh * S_LEN + q0 + c)) * DKV + g * 8;
  const half8 aA0 = *(const half8*)qpA;
  const half8 aA1 = *(const half8*)(qpA + 32);
  const _Float16* qpB = qpA + 16 * DKV;
  const half8 aB0 = *(const half8*)qpB;
  const half8 aB1 = *(const half8*)(qpB + 32);

  const _Float16* Kb = KH + (size_t)bh * S_LEN * DKV;
  const unsigned int* bq = bits + ((size_t)(bh * S_LEN + q0)) * (S_LEN / 32);

  float ZsA[4] = {0.0f, 0.0f, 0.0f, 0.0f};
  float ZsB[4] = {0.0f, 0.0f, 0.0f, 0.0f};

  const int kt0 = half * 32;   // this wave's 32 k-subtiles: [kt0, kt0+32)
  half8 k00a, k01a, k10a, k11a, k00b, k01b, k10b, k11b;

  // ---------------- pass 1: Z = sum over unmasked exp(s), pipelined --------
  LOADF(a, kt0);
  for (int sp = 0; sp < 16; ++sp) {
    const int s0 = kt0 + sp * 2;
    LOADF(b, s0 + 1);
    P1SUB(s0, a);
    if (sp < 15) LOADF(a, s0 + 2);
    P1SUB(s0 + 1, b);
  }

#pragma unroll
  for (int off = 1; off < 16; off <<= 1) {
#pragma unroll
    for (int e = 0; e < 4; e++) {
      ZsA[e] += __shfl_xor(ZsA[e], off, 64);
      ZsB[e] += __shfl_xor(ZsB[e], off, 64);
    }
  }
  if (c == 0) {
#pragma unroll
    for (int e = 0; e < 4; e++) {
      zbuf[tb][half][g * 4 + e] = ZsA[e];
      zbuf[tb][half][16 + g * 4 + e] = ZsB[e];
    }
  }
  __syncthreads();
  float lZA[4], lZB[4];
#pragma unroll
  for (int e = 0; e < 4; e++) {
    lZA[e] = __logf(zbuf[tb][0][g * 4 + e] + zbuf[tb][1][g * 4 + e]);
    lZB[e] = __logf(zbuf[tb][0][16 + g * 4 + e] + zbuf[tb][1][16 + g * 4 + e]);
  }

  // ---------------- pass 2: attn = exp(s - lnZ), PV, pipelined -------------
  f32x4 ctxA[4], ctxB[4];
#pragma unroll
  for (int nn = 0; nn < 4; nn++) { ctxA[nn] = (f32x4)0.0f; ctxB[nn] = (f32x4)0.0f; }

  const _Float16* Vb = VT + (size_t)bh * DKV * S_LEN;
  float* attn_base = out + CTX_ELEMS + ((size_t)(bh * S_LEN + q0)) * S_LEN;

  LOADF(a, kt0);
  for (int sp = 0; sp < 16; ++sp) {
    const int s0 = kt0 + sp * 2;
    LOADF(b, s0 + 1);
    P2SUB(s0, a);
    if (sp < 15) LOADF(a, s0 + 2);
    P2SUB(s0 + 1, b);
  }

  // ---------------- ctx combine across the two halves ----------------------
  __syncthreads();
  if (half == 1) {
#pragma unroll
    for (int nn = 0; nn < 4; nn++) {
#pragma unroll
      for (int e = 0; e < 4; e++) {
        cbuf[tb][g * 4 + e][nn * 16 + c] = ctxA[nn][e];
        cbuf[tb][16 + g * 4 + e][nn * 16 + c] = ctxB[nn][e];
      }
    }
  }
  __syncthreads();
  if (half == 0) {
    float* cb = out + ((size_t)(bh * S_LEN + q0)) * DKV;
#pragma unroll
    for (int nn = 0; nn < 4; nn++) {
#pragma unroll
      for (int e = 0; e < 4; e++) {
        float vA = ctxA[nn][e] + cbuf[tb][g * 4 + e][nn * 16 + c];
        float vB = ctxB[nn][e] + cbuf[tb][16 + g * 4 + e][nn * 16 + c];
        __builtin_nontemporal_store(vA, cb + (size_t)(g * 4 + e) * DKV + nn * 16 + c);
        __builtin_nontemporal_store(vB, cb + (size_t)(16 + g * 4 + e) * DKV + nn * 16 + c);
      }
    }
  }
}

// ---------------------------------------------------------------------------
// Fallback (R1 kernel) if ws is too small.
// ---------------------------------------------------------------------------
__global__ __launch_bounds__(512, 1)
void attn_slow_kernel(const float* __restrict__ Q, const float* __restrict__ K,
                      const float* __restrict__ V, const void* __restrict__ maskv,
                      float* __restrict__ out, const int* __restrict__ flag) {
  __shared__ __align__(16) unsigned char smem[16 * 2056 * 2];
  __shared__ float redm[8][16];
  __shared__ float reds[8][16];
  _Float16 (*P)[2056] = (_Float16 (*)[2056])smem;

  const int bh = blockIdx.y;
  const int q0 = blockIdx.x << 4;
  const int tid = threadIdx.x;
  const int w = tid >> 6;
  const int lane = tid & 63;
  const int g = lane >> 4;
  const int c = lane & 15;
  const int k0 = w << 8;

  const bool mask_w = (*flag) != 0;
  const unsigned char* m8 = (const unsigned char*)maskv;
  const unsigned int* m32 = (const unsigned int*)maskv;

  const float* Qb = Q + ((size_t)bh * S_LEN + q0) * DKV;
  const float* Kb = K + (size_t)bh * S_LEN * DKV;
  const float* Vb = V + (size_t)bh * S_LEN * DKV;
  const size_t mbase = ((size_t)bh * S_LEN + q0) * S_LEN;
  float* ctx_out = out + ((size_t)bh * S_LEN + q0) * DKV;
  float* attn_out = out + CTX_ELEMS + mbase;

  half8 a0, a1;
  {
    const float* qrow = Qb + (size_t)c * DKV + g * 8;
    f32x4 x0 = *(const f32x4*)(qrow);
    f32x4 x1 = *(const f32x4*)(qrow + 4);
    f32x4 y0 = *(const f32x4*)(qrow + 32);
    f32x4 y1 = *(const f32x4*)(qrow + 36);
#pragma unroll
    for (int j = 0; j < 4; j++) {
      a0[j] = (_Float16)x0[j]; a0[4 + j] = (_Float16)x1[j];
      a1[j] = (_Float16)y0[j]; a1[4 + j] = (_Float16)y1[j];
    }
  }

  f32x4 acc[16];
#pragma unroll
  for (int n = 0; n < 16; n++) acc[n] = (f32x4)0.0f;
#pragma unroll
  for (int n = 0; n < 16; n++) {
    const float* kr = Kb + (size_t)(k0 + n * 16 + c) * DKV + g * 8;
    f32x4 x0 = *(const f32x4*)(kr);
    f32x4 x1 = *(const f32x4*)(kr + 4);
    f32x4 y0 = *(const f32x4*)(kr + 32);
    f32x4 y1 = *(const f32x4*)(kr + 36);
    half8 b0, b1;
#pragma unroll
    for (int j = 0; j < 4; j++) {
      b0[j] = (_Float16)x0[j]; b0[4 + j] = (_Float16)x1[j];
      b1[j] = (_Float16)y0[j]; b1[4 + j] = (_Float16)y1[j];
    }
    acc[n] = MFMA16x32(a0, b0, acc[n]);
    acc[n] = MFMA16x32(a1, b1, acc[n]);
  }

  float mx[4] = {-1e9f, -1e9f, -1e9f, -1e9f};
#pragma unroll
  for (int n = 0; n < 16; n++) {
    const int kc = k0 + n * 16 + c;
#pragma unroll
    for (int e = 0; e < 4; e++) {
      const size_t mi = mbase + (size_t)(g * 4 + e) * S_LEN + kc;
      bool masked;
      if (mask_w) masked = (__builtin_nontemporal_load(&m32[mi]) != 0u);
      else        masked = (__builtin_nontemporal_load(&m8[mi]) != 0);
      float s = masked ? -1e9f : acc[n][e] * 0.125f;
      acc[n][e] = s;
      mx[e] = fmaxf(mx[e], s);
    }
  }
#pragma unroll
  for (int off = 1; off < 16; off <<= 1) {
#pragma unroll
    for (int e = 0; e < 4; e++)
      mx[e] = fmaxf(mx[e], __shfl_xor(mx[e], off, 64));
  }
  if (c == 0) {
#pragma unroll
    for (int e = 0; e < 4; e++) redm[w][g * 4 + e] = mx[e];
  }
  __syncthreads();
  float m[4], sm[4];
#pragma unroll
  for (int e = 0; e < 4; e++) {
    float v = redm[0][g * 4 + e];
#pragma unroll
    for (int ww = 1; ww < 8; ww++) v = fmaxf(v, redm[ww][g * 4 + e]);
    m[e] = v;
    sm[e] = 0.0f;
  }
#pragma unroll
  for (int n = 0; n < 16; n++) {
#pragma unroll
    for (int e = 0; e < 4; e++) {
      float p = __expf(acc[n][e] - m[e]);
      acc[n][e] = p;
      sm[e] += p;
    }
  }
#pragma unroll
  for (int off = 1; off < 16; off <<= 1) {
#pragma unroll
    for (int e = 0; e < 4; e++) sm[e] += __shfl_xor(sm[e], off, 64);
  }
  if (c == 0) {
#pragma unroll
    for (int e = 0; e < 4; e++) reds[w][g * 4 + e] = sm[e];
  }
  __syncthreads();
  float inv[4];
#pragma unroll
  for (int e = 0; e < 4; e++) {
    float z = 0.0f;
#pragma unroll
    for (int ww = 0; ww < 8; ww++) z += reds[ww][g * 4 + e];
    inv[e] = 1.0f / z;
  }
#pragma unroll
  for (int n = 0; n < 16; n++) {
    const int kc = k0 + n * 16 + c;
#pragma unroll
    for (int e = 0; e < 4; e++) {
      float v = acc[n][e] * inv[e];
      __builtin_nontemporal_store(v, &attn_out[(size_t)(g * 4 + e) * S_LEN + kc]);
      P[g * 4 + e][kc] = (_Float16)v;
    }
  }
  __syncthreads();

  f32x4 ctx[4];
#pragma unroll
  for (int n = 0; n < 4; n++) ctx[n] = (f32x4)0.0f;
  for (int ks = 0; ks < 8; ks++) {
    const int kb = k0 + ks * 32;
    half8 pa = *(const half8*)&P[c][kb + g * 8];
#pragma unroll
    for (int n = 0; n < 4; n++) {
      const float* vp = Vb + (size_t)(kb + g * 8) * DKV + n * 16 + c;
      half8 vb;
#pragma unroll
      for (int j = 0; j < 8; j++) vb[j] = (_Float16)vp[(size_t)j * DKV];
      ctx[n] = MFMA16x32(pa, vb, ctx[n]);
    }
  }
  __syncthreads();

  float* red2 = (float*)smem;
#pragma unroll
  for (int n = 0; n < 4; n++) {
#pragma unroll
    for (int e = 0; e < 4; e++)
      red2[((w * 16) + g * 4 + e) * 64 + n * 16 + c] = ctx[n][e];
  }
  __syncthreads();
  for (int i = tid; i < 16 * 64; i += 512) {
    int q = i >> 6, d = i & 63;
    float ssum = 0.0f;
#pragma unroll
    for (int ww = 0; ww < 8; ww++) ssum += red2[((ww * 16) + q) * 64 + d];
    ctx_out[(size_t)q * DKV + d] = ssum;
  }
}

extern "C" void kernel_launch(void* const* d_in, const int* in_sizes, int n_in,
                              void* d_out, int out_size, void* d_ws, size_t ws_size,
                              hipStream_t stream) {
  (void)in_sizes; (void)n_in; (void)out_size;
  const float* Q = (const float*)d_in[0];
  const float* K = (const float*)d_in[1];
  const float* V = (const float*)d_in[2];
  const void* mask = d_in[3];

  const size_t HBYTES = (size_t)NBH * S_LEN * DKV * sizeof(_Float16);       // 8 MB
  const size_t BITBYTES = (size_t)NBH * S_LEN * (S_LEN / 32) * 4;           // 16 MB
  const size_t NEED = 256 + 3 * HBYTES + BITBYTES;

  int* flag = (int*)d_ws;
  hipLaunchKernelGGL(detect_mask_kernel, dim3(1), dim3(512), 0, stream,
                     (const unsigned char*)mask, flag);

  if (ws_size >= NEED) {
    _Float16* QH = (_Float16*)((char*)d_ws + 256);
    _Float16* KH = (_Float16*)((char*)d_ws + 256 + HBYTES);
    _Float16* VT = (_Float16*)((char*)d_ws + 256 + 2 * HBYTES);
    unsigned int* bits = (unsigned int*)((char*)d_ws + 256 + 3 * HBYTES);
    const int n4 = NBH * S_LEN * DKV / 4;
    hipLaunchKernelGGL(pack_mask_kernel, dim3(2048), dim3(256), 0, stream,
                       mask, flag, bits);
    hipLaunchKernelGGL(convert_f32_f16_kernel, dim3(n4 / 256), dim3(256), 0, stream,
                       Q, QH, 0.125f);
    hipLaunchKernelGGL(convert_f32_f16_kernel, dim3(n4 / 256), dim3(256), 0, stream,
                       K, KH, 1.0f);
    hipLaunchKernelGGL(transpose_v_kernel, dim3(S_LEN / 64, NBH), dim3(256), 0, stream, V, VT);
    hipLaunchKernelGGL(attn_v10_kernel, dim3(512), dim3(512), 0, stream,
                       QH, KH, VT, bits, (float*)d_out);
  } else {
    hipLaunchKernelGGL(attn_slow_kernel, dim3(128, 32), dim3(512), 0, stream,
                       Q, K, V, mask, (float*)d_out, flag);
  }
}

// Round 13
// 350.289 us; speedup vs baseline: 1.2838x; 1.0025x over previous
//
#include <hip/hip_runtime.h>
#include <hip/hip_fp16.h>

#define S_LEN 2048
#define DKV 64
#define NBH 32
#define CTX_ELEMS ((size_t)NBH * S_LEN * DKV)

using half8 = __attribute__((ext_vector_type(8))) _Float16;
using half4 = __attribute__((ext_vector_type(4))) _Float16;
using f32x4 = __attribute__((ext_vector_type(4))) float;
using u32x4 = __attribute__((ext_vector_type(4))) unsigned int;

#define MFMA16x32(a, b, c) __builtin_amdgcn_mfma_f32_16x16x32_f16((a), (b), (c), 0, 0, 0)

// ---------------------------------------------------------------------------
// Runtime mask-dtype detection (1-byte bool vs 4-byte int/float 0/1).
// ---------------------------------------------------------------------------
__global__ void detect_mask_kernel(const unsigned char* __restrict__ mask,
                                   int* __restrict__ flag) {
  __shared__ int nz0s, nzos;
  if (threadIdx.x == 0) { nz0s = 0; nzos = 0; }
  __syncthreads();
  const u32x4* m = (const u32x4*)mask;
  unsigned int a0 = 0, ao = 0;
  for (int i = threadIdx.x; i < 8192; i += 512) {
    u32x4 v = m[i];
#pragma unroll
    for (int j = 0; j < 4; j++) {
      a0 |= v[j] & 0xffu;
      ao |= v[j] & 0xffffff00u;
    }
  }
  if (a0) atomicAdd(&nz0s, 1);
  if (ao) atomicAdd(&nzos, 1);
  __syncthreads();
  if (threadIdx.x == 0) *flag = (nz0s > 0 && nzos > 0) ? 0 : 1;
}

// ---------------------------------------------------------------------------
// Fused preprocessing: one kernel, block-range role dispatch so the four
// independent jobs overlap on hardware (pack is HBM-read-bound; converts
// and the V-transpose hide in its shadow).
//   blocks [0,2048)    : pack mask -> bits (16B/lane loads + 3x shfl_xor)
//   blocks [2048,2176) : Q f32 -> f16 * 0.125 (grid-stride)
//   blocks [2176,2304) : K f32 -> f16        (grid-stride)
//   blocks [2304,3328) : V [bh][k][d] f32 -> VT [bh][d][k] f16
// ---------------------------------------------------------------------------
#define PACK_B 2048
#define CONV_B 128
#define NF4 (NBH * S_LEN * DKV / 4)   // float4s per tensor = 1048576

__global__ void fused_pre_kernel(const void* __restrict__ maskv,
                                 const int* __restrict__ flag,
                                 unsigned int* __restrict__ bits,
                                 const float* __restrict__ Q, _Float16* __restrict__ QH,
                                 const float* __restrict__ K, _Float16* __restrict__ KH,
                                 const float* __restrict__ V, _Float16* __restrict__ VT) {
  __shared__ unsigned char nib[256];
  __shared__ _Float16 t[64][68];
  const int bidx = blockIdx.x;
  const int tid = threadIdx.x;

  if (bidx < PACK_B) {
    // ---------------- mask pack ----------------
    const bool w4 = (*flag) != 0;
    const unsigned int* m32 = (const unsigned int*)maskv;
    if (w4) {
      const int w = tid >> 6;
      const int lane = tid & 63;
      for (int it = 0; it < 64; ++it) {
        const size_t wb = ((size_t)bidx * 64 + it) * 1024 + (size_t)w * 256;
        u32x4 v = __builtin_nontemporal_load((const u32x4*)(m32 + wb + lane * 4));
        unsigned int x = ((v[0] ? 1u : 0u) | (v[1] ? 2u : 0u) |
                          (v[2] ? 4u : 0u) | (v[3] ? 8u : 0u)) << ((lane & 7) * 4);
        x |= __shfl_xor(x, 1, 64);
        x |= __shfl_xor(x, 2, 64);
        x |= __shfl_xor(x, 4, 64);
        if ((lane & 7) == 0)
          bits[(wb >> 5) + (lane >> 3)] = x;
      }
    } else {
      for (int it = 0; it < 64; ++it) {
        const size_t e0 = ((size_t)bidx * 64 + it) * 1024;
        const size_t ei = e0 + (size_t)tid * 4;
        unsigned int b = __builtin_nontemporal_load(m32 + (ei >> 2));
        unsigned int nv = ((b & 0xffu) ? 1u : 0u) | ((b & 0xff00u) ? 2u : 0u) |
                          ((b & 0xff0000u) ? 4u : 0u) | ((b & 0xff000000u) ? 8u : 0u);
        __syncthreads();
        nib[tid] = (unsigned char)nv;
        __syncthreads();
        if (tid < 32) {
          unsigned int dw = 0;
#pragma unroll
          for (int tt = 0; tt < 8; ++tt)
            dw |= ((unsigned int)nib[tid * 8 + tt]) << (tt * 4);
          bits[(e0 >> 5) + tid] = dw;
        }
      }
    }
  } else if (bidx < PACK_B + 2 * CONV_B) {
    // ---------------- Q/K fp32 -> fp16 (grid-stride) ----------------
    const bool isQ = bidx < PACK_B + CONV_B;
    const int cb = bidx - (isQ ? PACK_B : PACK_B + CONV_B);
    const float* src = isQ ? Q : K;
    _Float16* dst = isQ ? QH : KH;
    const float scale = isQ ? 0.125f : 1.0f;
    for (int i = cb * 256 + tid; i < NF4; i += CONV_B * 256) {
      f32x4 v = *(const f32x4*)(src + (size_t)i * 4);
      half4 h;
#pragma unroll
      for (int j = 0; j < 4; j++) h[j] = (_Float16)(v[j] * scale);
      *(half4*)(dst + (size_t)i * 4) = h;
    }
  } else {
    // ---------------- V transpose ----------------
    const int tIdx = bidx - (PACK_B + 2 * CONV_B);
    const int bh = tIdx >> 5;
    const int k0 = (tIdx & 31) * 64;
    const float* Vb = V + ((size_t)bh * S_LEN + k0) * DKV;
#pragma unroll
    for (int it = 0; it < 4; it++) {
      int idx = tid + it * 256;
      int kl = idx >> 4;
      int dq = (idx & 15) * 4;
      f32x4 v = *(const f32x4*)(Vb + (size_t)kl * DKV + dq);
#pragma unroll
      for (int j = 0; j < 4; j++) t[kl][dq + j] = (_Float16)v[j];
    }
    __syncthreads();
    _Float16* VTb = VT + (size_t)bh * DKV * S_LEN;
#pragma unroll
    for (int it = 0; it < 4; it++) {
      int idx = tid + it * 256;
      int d = idx >> 4;
      int kq = (idx & 15) * 4;
      half4 h;
#pragma unroll
      for (int j = 0; j < 4; j++) h[j] = t[kq + j][d];
      *(half4*)(VTb + (size_t)d * S_LEN + k0 + kq) = h;
    }
  }
}

// ---------------------------------------------------------------------------
// Main attention v10 (unchanged from R12's passing kernel): v9 + explicit
// 1-sub-lookahead K-fragment pipeline. Each wave owns a 32-row q-tile;
// 8 waves = 4 q32-tiles x 2 k-halves; no-max softmax; grid 512;
// lb(512,2) -> VGPR cap 128.
// ---------------------------------------------------------------------------
#define LOADF(S, KT) { \
  const _Float16* kp_ = Kb + ((size_t)((KT) * 32 + c)) * DKV + g * 8; \
  k00##S = *(const half8*)kp_; \
  k01##S = *(const half8*)(kp_ + 32); \
  k10##S = *(const half8*)(kp_ + 16 * DKV); \
  k11##S = *(const half8*)(kp_ + 16 * DKV + 32); }

#define P1SUB(KT, S) { \
  unsigned int mwA[4], mwB[4]; \
  _Pragma("unroll") for (int e = 0; e < 4; e++) { \
    mwA[e] = bq[(size_t)(g * 4 + e) * (S_LEN / 32) + (KT)]; \
    mwB[e] = bq[(size_t)(16 + g * 4 + e) * (S_LEN / 32) + (KT)]; } \
  f32x4 acA0 = (f32x4)0.0f, acA1 = (f32x4)0.0f; \
  f32x4 acB0 = (f32x4)0.0f, acB1 = (f32x4)0.0f; \
  acA0 = MFMA16x32(aA0, k00##S, acA0); \
  acA0 = MFMA16x32(aA1, k01##S, acA0); \
  acB0 = MFMA16x32(aB0, k00##S, acB0); \
  acB0 = MFMA16x32(aB1, k01##S, acB0); \
  acA1 = MFMA16x32(aA0, k10##S, acA1); \
  acA1 = MFMA16x32(aA1, k11##S, acA1); \
  acB1 = MFMA16x32(aB0, k10##S, acB1); \
  acB1 = MFMA16x32(aB1, k11##S, acB1); \
  _Pragma("unroll") for (int e = 0; e < 4; e++) { \
    float pA0 = ((mwA[e] >> c) & 1u) ? 0.0f : __expf(acA0[e]); \
    float pA1 = ((mwA[e] >> (16 + c)) & 1u) ? 0.0f : __expf(acA1[e]); \
    float pB0 = ((mwB[e] >> c) & 1u) ? 0.0f : __expf(acB0[e]); \
    float pB1 = ((mwB[e] >> (16 + c)) & 1u) ? 0.0f : __expf(acB1[e]); \
    ZsA[e] += pA0 + pA1; \
    ZsB[e] += pB0 + pB1; } }

#define P2SUB(KT, S) { \
  unsigned int mwA[4], mwB[4]; \
  _Pragma("unroll") for (int e = 0; e < 4; e++) { \
    mwA[e] = bq[(size_t)(g * 4 + e) * (S_LEN / 32) + (KT)]; \
    mwB[e] = bq[(size_t)(16 + g * 4 + e) * (S_LEN / 32) + (KT)]; } \
  half8 vb0 = *(const half8*)(Vb + (size_t)(0 * 16 + c) * S_LEN + (KT) * 32 + g * 8); \
  half8 vb1 = *(const half8*)(Vb + (size_t)(1 * 16 + c) * S_LEN + (KT) * 32 + g * 8); \
  half8 vb2 = *(const half8*)(Vb + (size_t)(2 * 16 + c) * S_LEN + (KT) * 32 + g * 8); \
  half8 vb3 = *(const half8*)(Vb + (size_t)(3 * 16 + c) * S_LEN + (KT) * 32 + g * 8); \
  f32x4 acA0 = (f32x4)0.0f, acA1 = (f32x4)0.0f; \
  f32x4 acB0 = (f32x4)0.0f, acB1 = (f32x4)0.0f; \
  acA0 = MFMA16x32(aA0, k00##S, acA0); \
  acA0 = MFMA16x32(aA1, k01##S, acA0); \
  acB0 = MFMA16x32(aB0, k00##S, acB0); \
  acB0 = MFMA16x32(aB1, k01##S, acB0); \
  acA1 = MFMA16x32(aA0, k10##S, acA1); \
  acA1 = MFMA16x32(aA1, k11##S, acA1); \
  acB1 = MFMA16x32(aB0, k10##S, acB1); \
  acB1 = MFMA16x32(aB1, k11##S, acB1); \
  _Pragma("unroll") for (int e = 0; e < 4; e++) { \
    float pA0 = ((mwA[e] >> c) & 1u) ? 0.0f : __expf(acA0[e] - lZA[e]); \
    float pA1 = ((mwA[e] >> (16 + c)) & 1u) ? 0.0f : __expf(acA1[e] - lZA[e]); \
    float pB0 = ((mwB[e] >> c) & 1u) ? 0.0f : __expf(acB0[e] - lZB[e]); \
    float pB1 = ((mwB[e] >> (16 + c)) & 1u) ? 0.0f : __expf(acB1[e] - lZB[e]); \
    pbuf[w][g * 4 + e][c] = (_Float16)pA0; \
    pbuf[w][g * 4 + e][16 + c] = (_Float16)pA1; \
    pbuf[w][16 + g * 4 + e][c] = (_Float16)pB0; \
    pbuf[w][16 + g * 4 + e][16 + c] = (_Float16)pB1; } \
  half8 paA = *(const half8*)&pbuf[w][c][g * 8]; \
  half8 paB = *(const half8*)&pbuf[w][16 + c][g * 8]; \
  _Pragma("unroll") for (int s = 0; s < 4; s++) { \
    const int r = (lane >> 3) + s * 8; \
    const int c4 = (lane & 7) * 4; \
    half4 h = *(const half4*)&pbuf[w][r][c4]; \
    f32x4 o; \
    _Pragma("unroll") for (int j = 0; j < 4; j++) o[j] = (float)h[j]; \
    __builtin_nontemporal_store(o, \
        (f32x4*)(attn_base + (size_t)r * S_LEN + (KT) * 32 + c4)); } \
  ctxA[0] = MFMA16x32(paA, vb0, ctxA[0]); \
  ctxB[0] = MFMA16x32(paB, vb0, ctxB[0]); \
  ctxA[1] = MFMA16x32(paA, vb1, ctxA[1]); \
  ctxB[1] = MFMA16x32(paB, vb1, ctxB[1]); \
  ctxA[2] = MFMA16x32(paA, vb2, ctxA[2]); \
  ctxB[2] = MFMA16x32(paB, vb2, ctxB[2]); \
  ctxA[3] = MFMA16x32(paA, vb3, ctxA[3]); \
  ctxB[3] = MFMA16x32(paB, vb3, ctxB[3]); }

__global__ __launch_bounds__(512, 2)
void attn_v10_kernel(const _Float16* __restrict__ QH, const _Float16* __restrict__ KH,
                     const _Float16* __restrict__ VT, const unsigned int* __restrict__ bits,
                     float* __restrict__ out) {
  __shared__ __align__(16) _Float16 pbuf[8][32][40];
  __shared__ float zbuf[4][2][32];
  __shared__ __align__(16) float cbuf[4][32][64];

  const int tid = threadIdx.x;
  const int w = tid >> 6;
  const int lane = tid & 63;
  const int g = lane >> 4;
  const int c = lane & 15;
  const int tb = w >> 1;
  const int half = w & 1;

  const int phys = blockIdx.x;
  const int orig = (phys & 7) * 64 + (phys >> 3);
  const int tile = orig * 4 + tb;
  const int bh = tile >> 6;
  const int q0 = (tile & 63) << 5;

  const _Float16* qpA = QH + ((size_t)(bh * S_LEN + q0 + c)) * DKV + g * 8;
  const half8 aA0 = *(const half8*)qpA;
  const half8 aA1 = *(const half8*)(qpA + 32);
  const _Float16* qpB = qpA + 16 * DKV;
  const half8 aB0 = *(const half8*)qpB;
  const half8 aB1 = *(const half8*)(qpB + 32);

  const _Float16* Kb = KH + (size_t)bh * S_LEN * DKV;
  const unsigned int* bq = bits + ((size_t)(bh * S_LEN + q0)) * (S_LEN / 32);

  float ZsA[4] = {0.0f, 0.0f, 0.0f, 0.0f};
  float ZsB[4] = {0.0f, 0.0f, 0.0f, 0.0f};

  const int kt0 = half * 32;
  half8 k00a, k01a, k10a, k11a, k00b, k01b, k10b, k11b;

  // ---------------- pass 1: Z = sum over unmasked exp(s), pipelined --------
  LOADF(a, kt0);
  for (int sp = 0; sp < 16; ++sp) {
    const int s0 = kt0 + sp * 2;
    LOADF(b, s0 + 1);
    P1SUB(s0, a);
    if (sp < 15) LOADF(a, s0 + 2);
    P1SUB(s0 + 1, b);
  }

#pragma unroll
  for (int off = 1; off < 16; off <<= 1) {
#pragma unroll
    for (int e = 0; e < 4; e++) {
      ZsA[e] += __shfl_xor(ZsA[e], off, 64);
      ZsB[e] += __shfl_xor(ZsB[e], off, 64);
    }
  }
  if (c == 0) {
#pragma unroll
    for (int e = 0; e < 4; e++) {
      zbuf[tb][half][g * 4 + e] = ZsA[e];
      zbuf[tb][half][16 + g * 4 + e] = ZsB[e];
    }
  }
  __syncthreads();
  float lZA[4], lZB[4];
#pragma unroll
  for (int e = 0; e < 4; e++) {
    lZA[e] = __logf(zbuf[tb][0][g * 4 + e] + zbuf[tb][1][g * 4 + e]);
    lZB[e] = __logf(zbuf[tb][0][16 + g * 4 + e] + zbuf[tb][1][16 + g * 4 + e]);
  }

  // ---------------- pass 2: attn = exp(s - lnZ), PV, pipelined -------------
  f32x4 ctxA[4], ctxB[4];
#pragma unroll
  for (int nn = 0; nn < 4; nn++) { ctxA[nn] = (f32x4)0.0f; ctxB[nn] = (f32x4)0.0f; }

  const _Float16* Vb = VT + (size_t)bh * DKV * S_LEN;
  float* attn_base = out + CTX_ELEMS + ((size_t)(bh * S_LEN + q0)) * S_LEN;

  LOADF(a, kt0);
  for (int sp = 0; sp < 16; ++sp) {
    const int s0 = kt0 + sp * 2;
    LOADF(b, s0 + 1);
    P2SUB(s0, a);
    if (sp < 15) LOADF(a, s0 + 2);
    P2SUB(s0 + 1, b);
  }

  // ---------------- ctx combine across the two halves ----------------------
  __syncthreads();
  if (half == 1) {
#pragma unroll
    for (int nn = 0; nn < 4; nn++) {
#pragma unroll
      for (int e = 0; e < 4; e++) {
        cbuf[tb][g * 4 + e][nn * 16 + c] = ctxA[nn][e];
        cbuf[tb][16 + g * 4 + e][nn * 16 + c] = ctxB[nn][e];
      }
    }
  }
  __syncthreads();
  if (half == 0) {
    float* cb = out + ((size_t)(bh * S_LEN + q0)) * DKV;
#pragma unroll
    for (int nn = 0; nn < 4; nn++) {
#pragma unroll
      for (int e = 0; e < 4; e++) {
        float vA = ctxA[nn][e] + cbuf[tb][g * 4 + e][nn * 16 + c];
        float vB = ctxB[nn][e] + cbuf[tb][16 + g * 4 + e][nn * 16 + c];
        __builtin_nontemporal_store(vA, cb + (size_t)(g * 4 + e) * DKV + nn * 16 + c);
        __builtin_nontemporal_store(vB, cb + (size_t)(16 + g * 4 + e) * DKV + nn * 16 + c);
      }
    }
  }
}

// ---------------------------------------------------------------------------
// Fallback (R1 kernel) if ws is too small.
// ---------------------------------------------------------------------------
__global__ __launch_bounds__(512, 1)
void attn_slow_kernel(const float* __restrict__ Q, const float* __restrict__ K,
                      const float* __restrict__ V, const void* __restrict__ maskv,
                      float* __restrict__ out, const int* __restrict__ flag) {
  __shared__ __align__(16) unsigned char smem[16 * 2056 * 2];
  __shared__ float redm[8][16];
  __shared__ float reds[8][16];
  _Float16 (*P)[2056] = (_Float16 (*)[2056])smem;

  const int bh = blockIdx.y;
  const int q0 = blockIdx.x << 4;
  const int tid = threadIdx.x;
  const int w = tid >> 6;
  const int lane = tid & 63;
  const int g = lane >> 4;
  const int c = lane & 15;
  const int k0 = w << 8;

  const bool mask_w = (*flag) != 0;
  const unsigned char* m8 = (const unsigned char*)maskv;
  const unsigned int* m32 = (const unsigned int*)maskv;

  const float* Qb = Q + ((size_t)bh * S_LEN + q0) * DKV;
  const float* Kb = K + (size_t)bh * S_LEN * DKV;
  const float* Vb = V + (size_t)bh * S_LEN * DKV;
  const size_t mbase = ((size_t)bh * S_LEN + q0) * S_LEN;
  float* ctx_out = out + ((size_t)bh * S_LEN + q0) * DKV;
  float* attn_out = out + CTX_ELEMS + mbase;

  half8 a0, a1;
  {
    const float* qrow = Qb + (size_t)c * DKV + g * 8;
    f32x4 x0 = *(const f32x4*)(qrow);
    f32x4 x1 = *(const f32x4*)(qrow + 4);
    f32x4 y0 = *(const f32x4*)(qrow + 32);
    f32x4 y1 = *(const f32x4*)(qrow + 36);
#pragma unroll
    for (int j = 0; j < 4; j++) {
      a0[j] = (_Float16)x0[j]; a0[4 + j] = (_Float16)x1[j];
      a1[j] = (_Float16)y0[j]; a1[4 + j] = (_Float16)y1[j];
    }
  }

  f32x4 acc[16];
#pragma unroll
  for (int n = 0; n < 16; n++) acc[n] = (f32x4)0.0f;
#pragma unroll
  for (int n = 0; n < 16; n++) {
    const float* kr = Kb + (size_t)(k0 + n * 16 + c) * DKV + g * 8;
    f32x4 x0 = *(const f32x4*)(kr);
    f32x4 x1 = *(const f32x4*)(kr + 4);
    f32x4 y0 = *(const f32x4*)(kr + 32);
    f32x4 y1 = *(const f32x4*)(kr + 36);
    half8 b0, b1;
#pragma unroll
    for (int j = 0; j < 4; j++) {
      b0[j] = (_Float16)x0[j]; b0[4 + j] = (_Float16)x1[j];
      b1[j] = (_Float16)y0[j]; b1[4 + j] = (_Float16)y1[j];
    }
    acc[n] = MFMA16x32(a0, b0, acc[n]);
    acc[n] = MFMA16x32(a1, b1, acc[n]);
  }

  float mx[4] = {-1e9f, -1e9f, -1e9f, -1e9f};
#pragma unroll
  for (int n = 0; n < 16; n++) {
    const int kc = k0 + n * 16 + c;
#pragma unroll
    for (int e = 0; e < 4; e++) {
      const size_t mi = mbase + (size_t)(g * 4 + e) * S_LEN + kc;
      bool masked;
      if (mask_w) masked = (__builtin_nontemporal_load(&m32[mi]) != 0u);
      else        masked = (__builtin_nontemporal_load(&m8[mi]) != 0);
      float s = masked ? -1e9f : acc[n][e] * 0.125f;
      acc[n][e] = s;
      mx[e] = fmaxf(mx[e], s);
    }
  }
#pragma unroll
  for (int off = 1; off < 16; off <<= 1) {
#pragma unroll
    for (int e = 0; e < 4; e++)
      mx[e] = fmaxf(mx[e], __shfl_xor(mx[e], off, 64));
  }
  if (c == 0) {
#pragma unroll
    for (int e = 0; e < 4; e++) redm[w][g * 4 + e] = mx[e];
  }
  __syncthreads();
  float m[4], sm[4];
#pragma unroll
  for (int e = 0; e < 4; e++) {
    float v = redm[0][g * 4 + e];
#pragma unroll
    for (int ww = 1; ww < 8; ww++) v = fmaxf(v, redm[ww][g * 4 + e]);
    m[e] = v;
    sm[e] = 0.0f;
  }
#pragma unroll
  for (int n = 0; n < 16; n++) {
#pragma unroll
    for (int e = 0; e < 4; e++) {
      float p = __expf(acc[n][e] - m[e]);
      acc[n][e] = p;
      sm[e] += p;
    }
  }
#pragma unroll
  for (int off = 1; off < 16; off <<= 1) {
#pragma unroll
    for (int e = 0; e < 4; e++) sm[e] += __shfl_xor(sm[e], off, 64);
  }
  if (c == 0) {
#pragma unroll
    for (int e = 0; e < 4; e++) reds[w][g * 4 + e] = sm[e];
  }
  __syncthreads();
  float inv[4];
#pragma unroll
  for (int e = 0; e < 4; e++) {
    float z = 0.0f;
#pragma unroll
    for (int ww = 0; ww < 8; ww++) z += reds[ww][g * 4 + e];
    inv[e] = 1.0f / z;
  }
#pragma unroll
  for (int n = 0; n < 16; n++) {
    const int kc = k0 + n * 16 + c;
#pragma unroll
    for (int e = 0; e < 4; e++) {
      float v = acc[n][e] * inv[e];
      __builtin_nontemporal_store(v, &attn_out[(size_t)(g * 4 + e) * S_LEN + kc]);
      P[g * 4 + e][kc] = (_Float16)v;
    }
  }
  __syncthreads();

  f32x4 ctx[4];
#pragma unroll
  for (int n = 0; n < 4; n++) ctx[n] = (f32x4)0.0f;
  for (int ks = 0; ks < 8; ks++) {
    const int kb = k0 + ks * 32;
    half8 pa = *(const half8*)&P[c][kb + g * 8];
#pragma unroll
    for (int n = 0; n < 4; n++) {
      const float* vp = Vb + (size_t)(kb + g * 8) * DKV + n * 16 + c;
      half8 vb;
#pragma unroll
      for (int j = 0; j < 8; j++) vb[j] = (_Float16)vp[(size_t)j * DKV];
      ctx[n] = MFMA16x32(pa, vb, ctx[n]);
    }
  }
  __syncthreads();

  float* red2 = (float*)smem;
#pragma unroll
  for (int n = 0; n < 4; n++) {
#pragma unroll
    for (int e = 0; e < 4; e++)
      red2[((w * 16) + g * 4 + e) * 64 + n * 16 + c] = ctx[n][e];
  }
  __syncthreads();
  for (int i = tid; i < 16 * 64; i += 512) {
    int q = i >> 6, d = i & 63;
    float ssum = 0.0f;
#pragma unroll
    for (int ww = 0; ww < 8; ww++) ssum += red2[((ww * 16) + q) * 64 + d];
    ctx_out[(size_t)q * DKV + d] = ssum;
  }
}

extern "C" void kernel_launch(void* const* d_in, const int* in_sizes, int n_in,
                              void* d_out, int out_size, void* d_ws, size_t ws_size,
                              hipStream_t stream) {
  (void)in_sizes; (void)n_in; (void)out_size;
  const float* Q = (const float*)d_in[0];
  const float* K = (const float*)d_in[1];
  const float* V = (const float*)d_in[2];
  const void* mask = d_in[3];

  const size_t HBYTES = (size_t)NBH * S_LEN * DKV * sizeof(_Float16);       // 8 MB
  const size_t BITBYTES = (size_t)NBH * S_LEN * (S_LEN / 32) * 4;           // 16 MB
  const size_t NEED = 256 + 3 * HBYTES + BITBYTES;

  int* flag = (int*)d_ws;
  hipLaunchKernelGGL(detect_mask_kernel, dim3(1), dim3(512), 0, stream,
                     (const unsigned char*)mask, flag);

  if (ws_size >= NEED) {
    _Float16* QH = (_Float16*)((char*)d_ws + 256);
    _Float16* KH = (_Float16*)((char*)d_ws + 256 + HBYTES);
    _Float16* VT = (_Float16*)((char*)d_ws + 256 + 2 * HBYTES);
    unsigned int* bits = (unsigned int*)((char*)d_ws + 256 + 3 * HBYTES);
    hipLaunchKernelGGL(fused_pre_kernel,
                       dim3(PACK_B + 2 * CONV_B + (S_LEN / 64) * NBH), dim3(256), 0, stream,
                       mask, flag, bits, Q, QH, K, KH, V, VT);
    hipLaunchKernelGGL(attn_v10_kernel, dim3(512), dim3(512), 0, stream,
                       QH, KH, VT, bits, (float*)d_out);
  } else {
    hipLaunchKernelGGL(attn_slow_kernel, dim3(128, 32), dim3(512), 0, stream,
                       Q, K, V, mask, (float*)d_out, flag);
  }
}